// Round 4
// baseline (151.560 us; speedup 1.0000x reference)
//
#include <hip/hip_runtime.h>
#include <stdint.h>
#include <stddef.h>

// Problem constants: B=4, T=2048, C=256, H=64, D=4
// rows = B*T = 8192 ; qkv row = 768 floats = [q(256)|k(256)|v(256)]

// ---------------------------------------------------------------------------
// Host-side replication of np.random.default_rng(1234) op-list generation.
// SeedSequence mix() is L*x - R*y (randutils seed_seq_fe). Verified (R2 pass).
// ---------------------------------------------------------------------------
static void compute_ops_host(int* kinds, int* wires) {
  const uint32_t MULT_A = 0x931e8875u;
  const uint32_t INIT_B = 0x8b51f9ddu, MULT_B = 0x58f38dedu;
  const uint32_t MIX_L = 0xca01f9ddu, MIX_R = 0x4973f715u;
  uint32_t hc = 0x43b0d7e5u; // INIT_A
  auto hashmix = [&](uint32_t v) -> uint32_t {
    v ^= hc; hc *= MULT_A; v *= hc; v ^= v >> 16; return v;
  };
  auto mix = [&](uint32_t x, uint32_t y) -> uint32_t {
    uint32_t r = (x * MIX_L) - (y * MIX_R); r ^= r >> 16; return r;
  };
  uint32_t pool[4];
  for (int i = 0; i < 4; ++i) pool[i] = hashmix(i == 0 ? 1234u : 0u);
  for (int s = 0; s < 4; ++s)
    for (int d = 0; d < 4; ++d)
      if (s != d) pool[d] = mix(pool[d], hashmix(pool[s]));
  uint32_t st32[8];
  uint32_t hcb = INIT_B;
  for (int i = 0; i < 8; ++i) {
    uint32_t dv = pool[i & 3];
    dv ^= hcb; hcb *= MULT_B; dv *= hcb; dv ^= dv >> 16;
    st32[i] = dv;
  }
  uint64_t s64[4];
  for (int k = 0; k < 4; ++k) s64[k] = (uint64_t)st32[2 * k] | ((uint64_t)st32[2 * k + 1] << 32);
  const __uint128_t M = ((__uint128_t)0x2360ed051fc65da4ULL << 64) | 0x4385df649fccf645ULL;
  __uint128_t initstate = ((__uint128_t)s64[0] << 64) | s64[1];
  __uint128_t inc = ((((__uint128_t)s64[2] << 64) | s64[3]) << 1) | (__uint128_t)1;
  __uint128_t state = inc;
  state += initstate;
  state = state * M + inc;
  bool has = false; uint32_t hbuf = 0;
  auto next32 = [&]() -> uint32_t {
    if (has) { has = false; return hbuf; }
    state = state * M + inc;
    uint64_t hi = (uint64_t)(state >> 64), lo = (uint64_t)state;
    uint64_t x = hi ^ lo;
    unsigned rot = (unsigned)(state >> 122) & 63u;
    uint64_t o = (x >> rot) | (x << ((64u - rot) & 63u));
    has = true; hbuf = (uint32_t)(o >> 32);
    return (uint32_t)o;
  };
  for (int i = 0; i < 20; ++i) {
    kinds[i] = (int)(((uint64_t)next32() * 4ull) >> 32); // 0=rx 1=ry 2=rz 3=cnot
    wires[i] = (int)(((uint64_t)next32() * 4ull) >> 32);
  }
}

// ---------------------------------------------------------------------------
// Build U (16x16 unitary), then M_w = Re(U^† D_w U), then the 3^4 tensors
// T[w][e1,e2,e3][e4] (e4 padded to 4) with z_w = sum T * prod_i t_i[e_i],
// t_i = (1, cos v_i, sin v_i).  One block, 256 threads, runs once.
// ---------------------------------------------------------------------------
__global__ __launch_bounds__(256) void build_tables(
    const float* __restrict__ rand_angles, const float* __restrict__ rx_theta,
    const float* __restrict__ ry_theta, unsigned long long kinds,
    unsigned long long wires, float* __restrict__ Tg)
{
  __shared__ float Ur[16][16], Ui[16][16];
  __shared__ float Msh[4][16][16];
  const int tid = threadIdx.x;
  {
    int i = tid >> 4, j = tid & 15;
    Ur[i][j] = (i == j) ? 1.0f : 0.0f;
    Ui[i][j] = 0.0f;
  }
  __syncthreads();
  for (int g = 0; g < 28; ++g) {
    int kind, w; float th;
    if (g < 20) {
      kind = (int)((kinds >> (2 * g)) & 3ull);
      w = (int)((wires >> (2 * g)) & 3ull);
      th = rand_angles[g];
    } else {
      int e = g - 20;
      w = e >> 1;
      kind = (e & 1) ? 1 : 0;
      th = (e & 1) ? ry_theta[0] : rx_theta[0];
    }
    if (kind == 3) {
      int mc = 8 >> w, mt = 8 >> ((w + 1) & 3);
      if (tid < 64) {
        int pi = tid >> 4, j = tid & 15;
        int i = mc, pbit = 0;
        for (int b = 3; b >= 0; --b) {
          int mask = 1 << b;
          if (mask != mc && mask != mt) { i |= ((pi >> pbit) & 1) << b; pbit++; }
        }
        int i2 = i | mt;
        float tr = Ur[i][j], ti = Ui[i][j];
        Ur[i][j] = Ur[i2][j]; Ui[i][j] = Ui[i2][j];
        Ur[i2][j] = tr; Ui[i2][j] = ti;
      }
    } else {
      float s, c;
      sincosf(th * 0.5f, &s, &c);
      float g00r, g00i, g01r, g01i, g10r, g10i, g11r, g11i;
      if (kind == 0) {        // RX
        g00r = c; g00i = 0; g01r = 0; g01i = -s; g10r = 0; g10i = -s; g11r = c; g11i = 0;
      } else if (kind == 1) { // RY
        g00r = c; g00i = 0; g01r = -s; g01i = 0; g10r = s; g10i = 0; g11r = c; g11i = 0;
      } else {                // RZ
        g00r = c; g00i = -s; g01r = 0; g01i = 0; g10r = 0; g10i = 0; g11r = c; g11i = s;
      }
      if (tid < 128) {
        int p = tid >> 4, j = tid & 15;
        int mb = 3 - w;
        int i0 = ((p >> mb) << (mb + 1)) | (p & ((1 << mb) - 1));
        int i1 = i0 | (1 << mb);
        float ar = Ur[i0][j], ai = Ui[i0][j];
        float br = Ur[i1][j], bi = Ui[i1][j];
        Ur[i0][j] = g00r * ar - g00i * ai + g01r * br - g01i * bi;
        Ui[i0][j] = g00r * ai + g00i * ar + g01r * bi + g01i * br;
        Ur[i1][j] = g10r * ar - g10i * ai + g11r * br - g11i * bi;
        Ui[i1][j] = g10r * ai + g10i * ar + g11r * bi + g11i * br;
      }
    }
    __syncthreads();
  }
  // Phase B: M_w[j][k] = sum_l sign_w(l) (Ur[l][j]Ur[l][k] + Ui[l][j]Ui[l][k])
  {
    int j = tid >> 4, k = tid & 15;
    float m0 = 0, m1 = 0, m2 = 0, m3 = 0;
#pragma unroll
    for (int l = 0; l < 16; ++l) {
      float p = Ur[l][j] * Ur[l][k] + Ui[l][j] * Ui[l][k];
      m0 += (l & 8) ? -p : p;
      m1 += (l & 4) ? -p : p;
      m2 += (l & 2) ? -p : p;
      m3 += (l & 1) ? -p : p;
    }
    Msh[0][j][k] = m0; Msh[1][j][k] = m1; Msh[2][j][k] = m2; Msh[3][j][k] = m3;
  }
  __syncthreads();
  // Phase C: T[w][r=(e1,e2,e3)][e4]
  if (tid < 81) {
    int e4 = tid % 3, r = tid / 3;
    int ee0 = r / 9, ee1 = (r / 3) % 3, ee2 = r % 3;
    int ee[4] = { ee0, ee1, ee2, e4 };
    float s0 = 0, s1 = 0, s2 = 0, s3 = 0;
    for (int m = 0; m < 16; ++m) {
      int j = 0, k = 0; float coef = 1.0f;
      for (int i = 0; i < 4; ++i) {
        int o = (m >> i) & 1;
        int e = ee[i];
        int bj, bk; float c;
        if (e == 2)      { bj = o; bk = 1 - o; c = 0.5f; }
        else if (e == 1) { bj = o; bk = o;     c = o ? -0.5f : 0.5f; }
        else             { bj = o; bk = o;     c = 0.5f; }
        j |= bj << (3 - i); k |= bk << (3 - i);
        coef *= c;
      }
      s0 += coef * Msh[0][j][k]; s1 += coef * Msh[1][j][k];
      s2 += coef * Msh[2][j][k]; s3 += coef * Msh[3][j][k];
    }
    Tg[(0 * 27 + r) * 4 + e4] = s0;
    Tg[(1 * 27 + r) * 4 + e4] = s1;
    Tg[(2 * 27 + r) * 4 + e4] = s2;
    Tg[(3 * 27 + r) * 4 + e4] = s3;
  }
  if (tid >= 81 && tid < 108) {   // zero the e4=3 pad
    int r = tid - 81;
    for (int w = 0; w < 4; ++w) Tg[(w * 27 + r) * 4 + 3] = 0.0f;
  }
}

// ---------------------------------------------------------------------------
// fp32 GEMM, 128x128 tile, BK=16, 8x8 microtile, split-K via blockIdx.z.
// C_partial[z][M][N] = A[:, z*klen:(z+1)*klen] @ B[:, same]^T.
// bias applied only when passed non-null (single-split launches).
// ---------------------------------------------------------------------------
__global__ __launch_bounds__(256) void gemm_nt128s(
    const float* __restrict__ A, const float* __restrict__ B,
    const float* __restrict__ bias, float* __restrict__ C,
    int M, int N, int K, int klen)
{
  __shared__ float As[16][136];
  __shared__ float Bs[16][136];
  const int bm = blockIdx.y * 128;
  const int bn = blockIdx.x * 128;
  const int kstart = blockIdx.z * klen;
  float* __restrict__ Cz = C + (size_t)blockIdx.z * M * N;
  const int tid = threadIdx.x;
  const int tx = tid & 15, ty = tid >> 4;
  float acc[8][8] = {};
  for (int k0 = kstart; k0 < kstart + klen; k0 += 16) {
#pragma unroll
    for (int i = 0; i < 2; ++i) {
      int idx = tid + i * 256;          // 512 float4 slots per tile
      int r = idx >> 2;                 // row 0..127
      int c = (idx & 3) << 2;           // col 0,4,8,12
      float4 va = *reinterpret_cast<const float4*>(&A[(size_t)(bm + r) * K + (k0 + c)]);
      As[c + 0][r] = va.x; As[c + 1][r] = va.y; As[c + 2][r] = va.z; As[c + 3][r] = va.w;
      float4 vb = *reinterpret_cast<const float4*>(&B[(size_t)(bn + r) * K + (k0 + c)]);
      Bs[c + 0][r] = vb.x; Bs[c + 1][r] = vb.y; Bs[c + 2][r] = vb.z; Bs[c + 3][r] = vb.w;
    }
    __syncthreads();
#pragma unroll
    for (int kk = 0; kk < 16; ++kk) {
      float4 a0 = *reinterpret_cast<const float4*>(&As[kk][ty << 2]);
      float4 a1 = *reinterpret_cast<const float4*>(&As[kk][64 + (ty << 2)]);
      float4 b0 = *reinterpret_cast<const float4*>(&Bs[kk][tx << 2]);
      float4 b1 = *reinterpret_cast<const float4*>(&Bs[kk][64 + (tx << 2)]);
      float av[8] = { a0.x, a0.y, a0.z, a0.w, a1.x, a1.y, a1.z, a1.w };
      float bv[8] = { b0.x, b0.y, b0.z, b0.w, b1.x, b1.y, b1.z, b1.w };
#pragma unroll
      for (int i = 0; i < 8; ++i)
#pragma unroll
        for (int j = 0; j < 8; ++j)
          acc[i][j] = fmaf(av[i], bv[j], acc[i][j]);
    }
    __syncthreads();
  }
  float4 bva = make_float4(0.f, 0.f, 0.f, 0.f), bvb = bva;
  if (bias != nullptr) {
    bva = *reinterpret_cast<const float4*>(&bias[bn + (tx << 2)]);
    bvb = *reinterpret_cast<const float4*>(&bias[bn + 64 + (tx << 2)]);
  }
#pragma unroll
  for (int i = 0; i < 8; ++i) {
    size_t r = (size_t)(bm + ((i < 4) ? ((ty << 2) + i) : (64 + (ty << 2) + i - 4)));
    float4 o0 = make_float4(acc[i][0] + bva.x, acc[i][1] + bva.y,
                            acc[i][2] + bva.z, acc[i][3] + bva.w);
    float4 o1 = make_float4(acc[i][4] + bvb.x, acc[i][5] + bvb.y,
                            acc[i][6] + bvb.z, acc[i][7] + bvb.w);
    *reinterpret_cast<float4*>(&Cz[r * N + bn + (tx << 2)]) = o0;
    *reinterpret_cast<float4*>(&Cz[r * N + bn + 64 + (tx << 2)]) = o1;
  }
}

// ---------------------------------------------------------------------------
// Quantum transform via tensor contraction; 4 vectors per thread.
// Reads p0 (+ optional split-K partial p1), writes result into p0.
// ---------------------------------------------------------------------------
__global__ __launch_bounds__(256) void quantum_apply4(
    float* __restrict__ p0, const float* __restrict__ p1,
    const float* __restrict__ Tg)
{
  __shared__ float Tsh[432];
  for (int i = threadIdx.x; i < 432; i += 256) Tsh[i] = Tg[i];
  __syncthreads();
  size_t base = ((size_t)blockIdx.x * 256 + threadIdx.x) * 16;
  float4 A0 = *reinterpret_cast<const float4*>(&p0[base]);
  float4 A1 = *reinterpret_cast<const float4*>(&p0[base + 4]);
  float4 A2 = *reinterpret_cast<const float4*>(&p0[base + 8]);
  float4 A3 = *reinterpret_cast<const float4*>(&p0[base + 12]);
  if (p1 != nullptr) {
    float4 B0 = *reinterpret_cast<const float4*>(&p1[base]);
    float4 B1 = *reinterpret_cast<const float4*>(&p1[base + 4]);
    float4 B2 = *reinterpret_cast<const float4*>(&p1[base + 8]);
    float4 B3 = *reinterpret_cast<const float4*>(&p1[base + 12]);
    A0.x += B0.x; A0.y += B0.y; A0.z += B0.z; A0.w += B0.w;
    A1.x += B1.x; A1.y += B1.y; A1.z += B1.z; A1.w += B1.w;
    A2.x += B2.x; A2.y += B2.y; A2.z += B2.z; A2.w += B2.w;
    A3.x += B3.x; A3.y += B3.y; A3.z += B3.z; A3.w += B3.w;
  }
  float ang[4][4] = {
    { A0.x, A0.y, A0.z, A0.w }, { A1.x, A1.y, A1.z, A1.w },
    { A2.x, A2.y, A2.z, A2.w }, { A3.x, A3.y, A3.z, A3.w } };
  float cv[4][4], sv[4][4];
#pragma unroll
  for (int v = 0; v < 4; ++v)
#pragma unroll
    for (int i = 0; i < 4; ++i)
      __sincosf(ang[v][i], &sv[v][i], &cv[v][i]);
  float z[4][4];
#pragma unroll
  for (int w = 0; w < 4; ++w) {
    float a1_[4] = { 0, 0, 0, 0 };
#pragma unroll
    for (int e1 = 0; e1 < 3; ++e1) {
      float a2_[4] = { 0, 0, 0, 0 };
#pragma unroll
      for (int e2 = 0; e2 < 3; ++e2) {
        float a3_[4] = { 0, 0, 0, 0 };
#pragma unroll
        for (int e3 = 0; e3 < 3; ++e3) {
          const float4 t4 = *reinterpret_cast<const float4*>(
              &Tsh[(w * 27 + e1 * 9 + e2 * 3 + e3) * 4]);
#pragma unroll
          for (int v = 0; v < 4; ++v) {
            float inner = fmaf(sv[v][3], t4.z, fmaf(cv[v][3], t4.y, t4.x));
            if (e3 == 0)      a3_[v] += inner;
            else if (e3 == 1) a3_[v] = fmaf(inner, cv[v][2], a3_[v]);
            else              a3_[v] = fmaf(inner, sv[v][2], a3_[v]);
          }
        }
#pragma unroll
        for (int v = 0; v < 4; ++v) {
          if (e2 == 0)      a2_[v] += a3_[v];
          else if (e2 == 1) a2_[v] = fmaf(a3_[v], cv[v][1], a2_[v]);
          else              a2_[v] = fmaf(a3_[v], sv[v][1], a2_[v]);
        }
      }
#pragma unroll
      for (int v = 0; v < 4; ++v) {
        if (e1 == 0)      a1_[v] += a2_[v];
        else if (e1 == 1) a1_[v] = fmaf(a2_[v], cv[v][0], a1_[v]);
        else              a1_[v] = fmaf(a2_[v], sv[v][0], a1_[v]);
      }
    }
#pragma unroll
    for (int v = 0; v < 4; ++v) z[v][w] = a1_[v];
  }
  *reinterpret_cast<float4*>(&p0[base])      = make_float4(z[0][0], z[0][1], z[0][2], z[0][3]);
  *reinterpret_cast<float4*>(&p0[base + 4])  = make_float4(z[1][0], z[1][1], z[1][2], z[1][3]);
  *reinterpret_cast<float4*>(&p0[base + 8])  = make_float4(z[2][0], z[2][1], z[2][2], z[2][3]);
  *reinterpret_cast<float4*>(&p0[base + 12]) = make_float4(z[3][0], z[3][1], z[3][2], z[3][3]);
}

// ---------------------------------------------------------------------------
// Attention across heads, zero-LDS: lane = head, k/v broadcast via readlane.
// Scores bounded (|q·k/2| <= 2 since z in [-1,1]) -> no max subtraction.
// ---------------------------------------------------------------------------
static __device__ __forceinline__ float rl(float x, int l) {
  return __int_as_float(__builtin_amdgcn_readlane(__float_as_int(x), l));
}

__global__ __launch_bounds__(256) void attn_rl(
    const float* __restrict__ qkv, float* __restrict__ y)
{
  const int wave = threadIdx.x >> 6, lane = threadIdx.x & 63;
  const int posIdx = blockIdx.x * 4 + wave;   // b*2048 + pos
  const float* row = qkv + (size_t)posIdx * 768;
  float4 q = *reinterpret_cast<const float4*>(&row[lane * 4]);
  float4 k = *reinterpret_cast<const float4*>(&row[256 + lane * 4]);
  float4 v = *reinterpret_cast<const float4*>(&row[512 + lane * 4]);
  float nx = 0, ny = 0, nz = 0, nw = 0, den = 0;
#pragma unroll
  for (int ss = 0; ss < 64; ++ss) {
    float kx = rl(k.x, ss), ky = rl(k.y, ss), kz = rl(k.z, ss), kw = rl(k.w, ss);
    float d = fmaf(q.x, kx, fmaf(q.y, ky, fmaf(q.z, kz, q.w * kw))) * 0.5f;
    float e = __expf(d);
    den += e;
    nx = fmaf(e, rl(v.x, ss), nx);
    ny = fmaf(e, rl(v.y, ss), ny);
    nz = fmaf(e, rl(v.z, ss), nz);
    nw = fmaf(e, rl(v.w, ss), nw);
  }
  float inv = 1.0f / den;
  const int b = posIdx >> 11, pos = posIdx & 2047;
  *reinterpret_cast<float4*>(&y[(((size_t)(b * 64 + lane)) * 2048 + pos) * 4]) =
      make_float4(nx * inv, ny * inv, nz * inv, nw * inv);
}

// ---------------------------------------------------------------------------
// Combine 4 split-K partials + bias -> out. One float4 per thread.
// ---------------------------------------------------------------------------
__global__ __launch_bounds__(256) void combine4(
    const float* __restrict__ g, const float* __restrict__ bias,
    float* __restrict__ out)
{
  const size_t PART = (size_t)8192 * 256;
  size_t i4 = (size_t)blockIdx.x * 256 + threadIdx.x;   // float4 index
  size_t off = i4 * 4;
  float4 a = *reinterpret_cast<const float4*>(&g[off]);
  float4 b = *reinterpret_cast<const float4*>(&g[PART + off]);
  float4 c = *reinterpret_cast<const float4*>(&g[2 * PART + off]);
  float4 d = *reinterpret_cast<const float4*>(&g[3 * PART + off]);
  float4 bi = *reinterpret_cast<const float4*>(&bias[(i4 & 63) * 4]);
  *reinterpret_cast<float4*>(&out[off]) = make_float4(
      a.x + b.x + c.x + d.x + bi.x, a.y + b.y + c.y + d.y + bi.y,
      a.z + b.z + c.z + d.z + bi.z, a.w + b.w + c.w + d.w + bi.w);
}

// ---------------------------------------------------------------------------
extern "C" void kernel_launch(void* const* d_in, const int* in_sizes, int n_in,
                              void* d_out, int out_size, void* d_ws, size_t ws_size,
                              hipStream_t stream)
{
  const float* x    = (const float*)d_in[0];
  const float* wqkv = (const float*)d_in[1];
  const float* wout = (const float*)d_in[2];
  const float* bout = (const float*)d_in[3];
  const float* rxth = (const float*)d_in[4];
  const float* ryth = (const float*)d_in[5];
  const float* rang = (const float*)d_in[6];
  float* out = (float*)d_out;

  const size_t QKV = (size_t)8192 * 768;   // 6291456 floats
  const size_t YSZ = (size_t)8192 * 256;   // 2097152 floats

  int kinds[20], wires[20];
  compute_ops_host(kinds, wires);
  unsigned long long pk = 0, pw = 0;
  for (int i = 0; i < 20; ++i) {
    pk |= (unsigned long long)(kinds[i] & 3) << (2 * i);
    pw |= (unsigned long long)(wires[i] & 3) << (2 * i);
  }

  // Plan A layout: Tg(1024) | p0(QKV) | p1(QKV) | y(YSZ) | g(4*YSZ)
  const size_t needA = (1024 + 2 * QKV + YSZ + 4 * YSZ) * sizeof(float);
  float* Tg = (float*)d_ws;

  hipLaunchKernelGGL(build_tables, dim3(1), dim3(256), 0, stream,
                     rang, rxth, ryth, pk, pw, Tg);

  if (ws_size >= needA) {
    float* p0 = Tg + 1024;
    float* p1 = p0 + QKV;
    float* y  = p1 + QKV;
    float* g  = y + YSZ;
    // gemm1 split-K=2: 6x64x2 = 768 blocks (exactly 3/CU)
    hipLaunchKernelGGL(gemm_nt128s, dim3(6, 64, 2), dim3(256), 0, stream,
                       x, wqkv, (const float*)nullptr, p0, 8192, 768, 256, 128);
    hipLaunchKernelGGL(quantum_apply4, dim3(1536), dim3(256), 0, stream,
                       p0, (const float*)p1, Tg);
    hipLaunchKernelGGL(attn_rl, dim3(2048), dim3(256), 0, stream, p0, y);
    // gemm2 split-K=4: 2x64x4 = 512 blocks (2/CU)
    hipLaunchKernelGGL(gemm_nt128s, dim3(2, 64, 4), dim3(256), 0, stream,
                       y, wout, (const float*)nullptr, g, 8192, 256, 256, 64);
    hipLaunchKernelGGL(combine4, dim3(2048), dim3(256), 0, stream, g, bout, out);
  } else {
    // Fallback: no split-K (fits in 33.6MB like R3)
    float* p0 = Tg + 1024;
    float* y  = p0 + QKV;
    hipLaunchKernelGGL(gemm_nt128s, dim3(6, 64, 1), dim3(256), 0, stream,
                       x, wqkv, (const float*)nullptr, p0, 8192, 768, 256, 256);
    hipLaunchKernelGGL(quantum_apply4, dim3(1536), dim3(256), 0, stream,
                       p0, (const float*)nullptr, Tg);
    hipLaunchKernelGGL(attn_rl, dim3(2048), dim3(256), 0, stream, p0, y);
    hipLaunchKernelGGL(gemm_nt128s, dim3(2, 64, 1), dim3(256), 0, stream,
                       y, wout, bout, out, 8192, 256, 256, 256);
  }
}

// Round 5
// 115.823 us; speedup vs baseline: 1.3085x; 1.3085x over previous
//
#include <hip/hip_runtime.h>
#include <stdint.h>
#include <stddef.h>

// B=4, T=2048, C=256, H=64, D=4 ; rows = 8192 ; qkv row = [q|k|v] 768 f
typedef __attribute__((ext_vector_type(8))) short short8;
typedef __attribute__((ext_vector_type(4))) float floatx4;

// ---------------------------------------------------------------------------
// Host-side np.random.default_rng(1234) op list (verified R2).
// ---------------------------------------------------------------------------
static void compute_ops_host(int* kinds, int* wires) {
  const uint32_t MULT_A = 0x931e8875u;
  const uint32_t INIT_B = 0x8b51f9ddu, MULT_B = 0x58f38dedu;
  const uint32_t MIX_L = 0xca01f9ddu, MIX_R = 0x4973f715u;
  uint32_t hc = 0x43b0d7e5u;
  auto hashmix = [&](uint32_t v) -> uint32_t {
    v ^= hc; hc *= MULT_A; v *= hc; v ^= v >> 16; return v;
  };
  auto mix = [&](uint32_t x, uint32_t y) -> uint32_t {
    uint32_t r = (x * MIX_L) - (y * MIX_R); r ^= r >> 16; return r;
  };
  uint32_t pool[4];
  for (int i = 0; i < 4; ++i) pool[i] = hashmix(i == 0 ? 1234u : 0u);
  for (int s = 0; s < 4; ++s)
    for (int d = 0; d < 4; ++d)
      if (s != d) pool[d] = mix(pool[d], hashmix(pool[s]));
  uint32_t st32[8];
  uint32_t hcb = INIT_B;
  for (int i = 0; i < 8; ++i) {
    uint32_t dv = pool[i & 3];
    dv ^= hcb; hcb *= MULT_B; dv *= hcb; dv ^= dv >> 16;
    st32[i] = dv;
  }
  uint64_t s64[4];
  for (int k = 0; k < 4; ++k) s64[k] = (uint64_t)st32[2 * k] | ((uint64_t)st32[2 * k + 1] << 32);
  const __uint128_t M = ((__uint128_t)0x2360ed051fc65da4ULL << 64) | 0x4385df649fccf645ULL;
  __uint128_t initstate = ((__uint128_t)s64[0] << 64) | s64[1];
  __uint128_t inc = ((((__uint128_t)s64[2] << 64) | s64[3]) << 1) | (__uint128_t)1;
  __uint128_t state = inc;
  state += initstate;
  state = state * M + inc;
  bool has = false; uint32_t hbuf = 0;
  auto next32 = [&]() -> uint32_t {
    if (has) { has = false; return hbuf; }
    state = state * M + inc;
    uint64_t hi = (uint64_t)(state >> 64), lo = (uint64_t)state;
    uint64_t x = hi ^ lo;
    unsigned rot = (unsigned)(state >> 122) & 63u;
    uint64_t o = (x >> rot) | (x << ((64u - rot) & 63u));
    has = true; hbuf = (uint32_t)(o >> 32);
    return (uint32_t)o;
  };
  for (int i = 0; i < 20; ++i) {
    kinds[i] = (int)(((uint64_t)next32() * 4ull) >> 32);
    wires[i] = (int)(((uint64_t)next32() * 4ull) >> 32);
  }
}

// ---------------------------------------------------------------------------
// Build the 3^4 contraction tensors T[w][27][4] from the fixed circuit.
// ---------------------------------------------------------------------------
__global__ __launch_bounds__(256) void build_tables(
    const float* __restrict__ rand_angles, const float* __restrict__ rx_theta,
    const float* __restrict__ ry_theta, unsigned long long kinds,
    unsigned long long wires, float* __restrict__ Tg)
{
  __shared__ float Ur[16][16], Ui[16][16];
  __shared__ float Msh[4][16][16];
  const int tid = threadIdx.x;
  {
    int i = tid >> 4, j = tid & 15;
    Ur[i][j] = (i == j) ? 1.0f : 0.0f;
    Ui[i][j] = 0.0f;
  }
  __syncthreads();
  for (int g = 0; g < 28; ++g) {
    int kind, w; float th;
    if (g < 20) {
      kind = (int)((kinds >> (2 * g)) & 3ull);
      w = (int)((wires >> (2 * g)) & 3ull);
      th = rand_angles[g];
    } else {
      int e = g - 20;
      w = e >> 1;
      kind = (e & 1) ? 1 : 0;
      th = (e & 1) ? ry_theta[0] : rx_theta[0];
    }
    if (kind == 3) {
      int mc = 8 >> w, mt = 8 >> ((w + 1) & 3);
      if (tid < 64) {
        int pi = tid >> 4, j = tid & 15;
        int i = mc, pbit = 0;
        for (int b = 3; b >= 0; --b) {
          int mask = 1 << b;
          if (mask != mc && mask != mt) { i |= ((pi >> pbit) & 1) << b; pbit++; }
        }
        int i2 = i | mt;
        float tr = Ur[i][j], ti = Ui[i][j];
        Ur[i][j] = Ur[i2][j]; Ui[i][j] = Ui[i2][j];
        Ur[i2][j] = tr; Ui[i2][j] = ti;
      }
    } else {
      float s, c;
      sincosf(th * 0.5f, &s, &c);
      float g00r, g00i, g01r, g01i, g10r, g10i, g11r, g11i;
      if (kind == 0) {
        g00r = c; g00i = 0; g01r = 0; g01i = -s; g10r = 0; g10i = -s; g11r = c; g11i = 0;
      } else if (kind == 1) {
        g00r = c; g00i = 0; g01r = -s; g01i = 0; g10r = s; g10i = 0; g11r = c; g11i = 0;
      } else {
        g00r = c; g00i = -s; g01r = 0; g01i = 0; g10r = 0; g10i = 0; g11r = c; g11i = s;
      }
      if (tid < 128) {
        int p = tid >> 4, j = tid & 15;
        int mb = 3 - w;
        int i0 = ((p >> mb) << (mb + 1)) | (p & ((1 << mb) - 1));
        int i1 = i0 | (1 << mb);
        float ar = Ur[i0][j], ai = Ui[i0][j];
        float br = Ur[i1][j], bi = Ui[i1][j];
        Ur[i0][j] = g00r * ar - g00i * ai + g01r * br - g01i * bi;
        Ui[i0][j] = g00r * ai + g00i * ar + g01r * bi + g01i * br;
        Ur[i1][j] = g10r * ar - g10i * ai + g11r * br - g11i * bi;
        Ui[i1][j] = g10r * ai + g10i * ar + g11r * bi + g11i * br;
      }
    }
    __syncthreads();
  }
  {
    int j = tid >> 4, k = tid & 15;
    float m0 = 0, m1 = 0, m2 = 0, m3 = 0;
#pragma unroll
    for (int l = 0; l < 16; ++l) {
      float p = Ur[l][j] * Ur[l][k] + Ui[l][j] * Ui[l][k];
      m0 += (l & 8) ? -p : p;
      m1 += (l & 4) ? -p : p;
      m2 += (l & 2) ? -p : p;
      m3 += (l & 1) ? -p : p;
    }
    Msh[0][j][k] = m0; Msh[1][j][k] = m1; Msh[2][j][k] = m2; Msh[3][j][k] = m3;
  }
  __syncthreads();
  if (tid < 81) {
    int e4 = tid % 3, r = tid / 3;
    int ee0 = r / 9, ee1 = (r / 3) % 3, ee2 = r % 3;
    int ee[4] = { ee0, ee1, ee2, e4 };
    float s0 = 0, s1 = 0, s2 = 0, s3 = 0;
    for (int m = 0; m < 16; ++m) {
      int j = 0, k = 0; float coef = 1.0f;
      for (int i = 0; i < 4; ++i) {
        int o = (m >> i) & 1;
        int e = ee[i];
        int bj, bk; float c;
        if (e == 2)      { bj = o; bk = 1 - o; c = 0.5f; }
        else if (e == 1) { bj = o; bk = o;     c = o ? -0.5f : 0.5f; }
        else             { bj = o; bk = o;     c = 0.5f; }
        j |= bj << (3 - i); k |= bk << (3 - i);
        coef *= c;
      }
      s0 += coef * Msh[0][j][k]; s1 += coef * Msh[1][j][k];
      s2 += coef * Msh[2][j][k]; s3 += coef * Msh[3][j][k];
    }
    Tg[(0 * 27 + r) * 4 + e4] = s0;
    Tg[(1 * 27 + r) * 4 + e4] = s1;
    Tg[(2 * 27 + r) * 4 + e4] = s2;
    Tg[(3 * 27 + r) * 4 + e4] = s3;
  }
  if (tid >= 81 && tid < 108) {
    int r = tid - 81;
    for (int w = 0; w < 4; ++w) Tg[(w * 27 + r) * 4 + 3] = 0.0f;
  }
}

// ---------------------------------------------------------------------------
// bf16 hi/lo split helpers (round-to-nearest-even-ish via magic add).
// ---------------------------------------------------------------------------
static __device__ __forceinline__ unsigned short bf16_rn(float x) {
  uint32_t u = __float_as_uint(x);
  return (unsigned short)((u + 0x7FFFu + ((u >> 16) & 1u)) >> 16);
}
static __device__ __forceinline__ void split2(float x, unsigned short& h, unsigned short& l) {
  h = bf16_rn(x);
  float hf = __uint_as_float(((uint32_t)h) << 16);
  l = bf16_rn(x - hf);
}

// Convert fp32 array -> bf16 hi + lo arrays. One float4 per thread.
__global__ __launch_bounds__(256) void conv_split(
    const float* __restrict__ in, unsigned short* __restrict__ h,
    unsigned short* __restrict__ l, int n4)
{
  int i = blockIdx.x * 256 + threadIdx.x;
  if (i >= n4) return;
  float4 v = *reinterpret_cast<const float4*>(&in[(size_t)i * 4]);
  ushort4 hh, ll;
  split2(v.x, hh.x, ll.x);
  split2(v.y, hh.y, ll.y);
  split2(v.z, hh.z, ll.z);
  split2(v.w, hh.w, ll.w);
  *reinterpret_cast<ushort4*>(&h[(size_t)i * 4]) = hh;
  *reinterpret_cast<ushort4*>(&l[(size_t)i * 4]) = ll;
}

// ---------------------------------------------------------------------------
// MFMA split-bf16 GEMM: C[M,N] = A[M,K] @ B[N,K]^T (+bias), fp32-accurate via
// Ah*Bh + Ah*Bl + Al*Bh. BM=128, BN=64, BK=32; 4 waves (2m x 2n), wave-tile
// 64x32 (4x2 16x16 frags). A,B are bf16 row-major K-contig.
// ---------------------------------------------------------------------------
__global__ __launch_bounds__(256) void gemm_mfma_split(
    const unsigned short* __restrict__ Ah, const unsigned short* __restrict__ Al,
    const unsigned short* __restrict__ Bh, const unsigned short* __restrict__ Bl,
    const float* __restrict__ bias, float* __restrict__ C,
    int M, int N, int K)
{
  __shared__ __align__(16) unsigned short sAh[128 * 32];
  __shared__ __align__(16) unsigned short sAl[128 * 32];
  __shared__ __align__(16) unsigned short sBh[64 * 32];
  __shared__ __align__(16) unsigned short sBl[64 * 32];
  const int tid = threadIdx.x;
  const int bm = blockIdx.y * 128, bn = blockIdx.x * 64;
  const int wave = tid >> 6, lane = tid & 63;
  const int wm = wave >> 1, wn = wave & 1;
  const int fr = lane & 15, fg = lane >> 4;
  floatx4 acc[4][2] = {};
  for (int k0 = 0; k0 < K; k0 += 32) {
    __syncthreads();
    // stage A: 128 rows x 32 cols bf16 = 512 x 16B chunks (2 rounds)
#pragma unroll
    for (int rd = 0; rd < 2; ++rd) {
      int q = tid + rd * 256;
      int r = q >> 2, c8 = (q & 3) * 8;
      size_t go = (size_t)(bm + r) * K + (k0 + c8);
      *reinterpret_cast<uint4*>(&sAh[q * 8]) = *reinterpret_cast<const uint4*>(&Ah[go]);
      *reinterpret_cast<uint4*>(&sAl[q * 8]) = *reinterpret_cast<const uint4*>(&Al[go]);
    }
    // stage B: 64 rows x 32 cols = 256 chunks (1 round)
    {
      int r = tid >> 2, c8 = (tid & 3) * 8;
      size_t go = (size_t)(bn + r) * K + (k0 + c8);
      *reinterpret_cast<uint4*>(&sBh[tid * 8]) = *reinterpret_cast<const uint4*>(&Bh[go]);
      *reinterpret_cast<uint4*>(&sBl[tid * 8]) = *reinterpret_cast<const uint4*>(&Bl[go]);
    }
    __syncthreads();
    short8 a_h[4], a_l[4], b_h[2], b_l[2];
#pragma unroll
    for (int fm = 0; fm < 4; ++fm) {
      int row = wm * 64 + fm * 16 + fr;
      a_h[fm] = *reinterpret_cast<const short8*>(&sAh[row * 32 + fg * 8]);
      a_l[fm] = *reinterpret_cast<const short8*>(&sAl[row * 32 + fg * 8]);
    }
#pragma unroll
    for (int fn = 0; fn < 2; ++fn) {
      int row = wn * 32 + fn * 16 + fr;
      b_h[fn] = *reinterpret_cast<const short8*>(&sBh[row * 32 + fg * 8]);
      b_l[fn] = *reinterpret_cast<const short8*>(&sBl[row * 32 + fg * 8]);
    }
#pragma unroll
    for (int fm = 0; fm < 4; ++fm)
#pragma unroll
      for (int fn = 0; fn < 2; ++fn) {
        acc[fm][fn] = __builtin_amdgcn_mfma_f32_16x16x32_bf16(a_h[fm], b_h[fn], acc[fm][fn], 0, 0, 0);
        acc[fm][fn] = __builtin_amdgcn_mfma_f32_16x16x32_bf16(a_h[fm], b_l[fn], acc[fm][fn], 0, 0, 0);
        acc[fm][fn] = __builtin_amdgcn_mfma_f32_16x16x32_bf16(a_l[fm], b_h[fn], acc[fm][fn], 0, 0, 0);
      }
  }
  // epilogue: C/D map col=lane&15, row=(lane>>4)*4+reg (guide, HW-verified)
#pragma unroll
  for (int fm = 0; fm < 4; ++fm) {
    int rowb = bm + wm * 64 + fm * 16 + fg * 4;
#pragma unroll
    for (int fn = 0; fn < 2; ++fn) {
      int col = bn + wn * 32 + fn * 16 + fr;
      float bv = (bias != nullptr) ? bias[col] : 0.0f;
#pragma unroll
      for (int r = 0; r < 4; ++r)
        C[(size_t)(rowb + r) * N + col] = acc[fm][fn][r] + bv;
    }
  }
}

// ---------------------------------------------------------------------------
// Quantum transform via 3^4 tensor contraction; 4 vectors/thread, in-place.
// ---------------------------------------------------------------------------
__global__ __launch_bounds__(256) void quantum_apply4(
    float* __restrict__ p0, const float* __restrict__ Tg)
{
  __shared__ float Tsh[432];
  for (int i = threadIdx.x; i < 432; i += 256) Tsh[i] = Tg[i];
  __syncthreads();
  size_t base = ((size_t)blockIdx.x * 256 + threadIdx.x) * 16;
  float4 A0 = *reinterpret_cast<const float4*>(&p0[base]);
  float4 A1 = *reinterpret_cast<const float4*>(&p0[base + 4]);
  float4 A2 = *reinterpret_cast<const float4*>(&p0[base + 8]);
  float4 A3 = *reinterpret_cast<const float4*>(&p0[base + 12]);
  float ang[4][4] = {
    { A0.x, A0.y, A0.z, A0.w }, { A1.x, A1.y, A1.z, A1.w },
    { A2.x, A2.y, A2.z, A2.w }, { A3.x, A3.y, A3.z, A3.w } };
  float cv[4][4], sv[4][4];
#pragma unroll
  for (int v = 0; v < 4; ++v)
#pragma unroll
    for (int i = 0; i < 4; ++i)
      __sincosf(ang[v][i], &sv[v][i], &cv[v][i]);
  float z[4][4];
#pragma unroll
  for (int w = 0; w < 4; ++w) {
    float a1_[4] = { 0, 0, 0, 0 };
#pragma unroll
    for (int e1 = 0; e1 < 3; ++e1) {
      float a2_[4] = { 0, 0, 0, 0 };
#pragma unroll
      for (int e2 = 0; e2 < 3; ++e2) {
        float a3_[4] = { 0, 0, 0, 0 };
#pragma unroll
        for (int e3 = 0; e3 < 3; ++e3) {
          const float4 t4 = *reinterpret_cast<const float4*>(
              &Tsh[(w * 27 + e1 * 9 + e2 * 3 + e3) * 4]);
#pragma unroll
          for (int v = 0; v < 4; ++v) {
            float inner = fmaf(sv[v][3], t4.z, fmaf(cv[v][3], t4.y, t4.x));
            if (e3 == 0)      a3_[v] += inner;
            else if (e3 == 1) a3_[v] = fmaf(inner, cv[v][2], a3_[v]);
            else              a3_[v] = fmaf(inner, sv[v][2], a3_[v]);
          }
        }
#pragma unroll
        for (int v = 0; v < 4; ++v) {
          if (e2 == 0)      a2_[v] += a3_[v];
          else if (e2 == 1) a2_[v] = fmaf(a3_[v], cv[v][1], a2_[v]);
          else              a2_[v] = fmaf(a3_[v], sv[v][1], a2_[v]);
        }
      }
#pragma unroll
      for (int v = 0; v < 4; ++v) {
        if (e1 == 0)      a1_[v] += a2_[v];
        else if (e1 == 1) a1_[v] = fmaf(a2_[v], cv[v][0], a1_[v]);
        else              a1_[v] = fmaf(a2_[v], sv[v][0], a1_[v]);
      }
    }
#pragma unroll
    for (int v = 0; v < 4; ++v) z[v][w] = a1_[v];
  }
  *reinterpret_cast<float4*>(&p0[base])      = make_float4(z[0][0], z[0][1], z[0][2], z[0][3]);
  *reinterpret_cast<float4*>(&p0[base + 4])  = make_float4(z[1][0], z[1][1], z[1][2], z[1][3]);
  *reinterpret_cast<float4*>(&p0[base + 8])  = make_float4(z[2][0], z[2][1], z[2][2], z[2][3]);
  *reinterpret_cast<float4*>(&p0[base + 12]) = make_float4(z[3][0], z[3][1], z[3][2], z[3][3]);
}

// ---------------------------------------------------------------------------
// Attention across heads (LDS variant, proven): per (b,pos): softmax over
// S=QK^T/2 (64x64), Y = A V. Outputs bf16 hi/lo in (B,H,T,D) flat layout.
// ---------------------------------------------------------------------------
__global__ __launch_bounds__(256) void attn64b(
    const float* __restrict__ qkv, unsigned short* __restrict__ yh,
    unsigned short* __restrict__ yl)
{
  __shared__ float Ksh[4][64][4];
  __shared__ float Vsh[4][64][4];
  const int wave = threadIdx.x >> 6, lane = threadIdx.x & 63;
  const int posIdx = blockIdx.x * 4 + wave;   // b*2048 + pos
  const float* row = qkv + (size_t)posIdx * 768;
  float4 q = *reinterpret_cast<const float4*>(&row[lane * 4]);
  *reinterpret_cast<float4*>(&Ksh[wave][lane][0]) =
      *reinterpret_cast<const float4*>(&row[256 + lane * 4]);
  *reinterpret_cast<float4*>(&Vsh[wave][lane][0]) =
      *reinterpret_cast<const float4*>(&row[512 + lane * 4]);
  __syncthreads();
  // |z| <= 1 -> |score| <= 2 : softmax needs no max subtraction
  float nx = 0, ny = 0, nz = 0, nw = 0, den = 0;
#pragma unroll
  for (int ss = 0; ss < 64; ++ss) {
    float d = q.x * Ksh[wave][ss][0] + q.y * Ksh[wave][ss][1] +
              q.z * Ksh[wave][ss][2] + q.w * Ksh[wave][ss][3];
    float e = __expf(d * 0.5f);
    den += e;
    nx = fmaf(e, Vsh[wave][ss][0], nx);
    ny = fmaf(e, Vsh[wave][ss][1], ny);
    nz = fmaf(e, Vsh[wave][ss][2], nz);
    nw = fmaf(e, Vsh[wave][ss][3], nw);
  }
  float inv = 1.0f / den;
  const int b = posIdx >> 11, pos = posIdx & 2047;
  size_t off = (((size_t)(b * 64 + lane)) * 2048 + pos) * 4;
  ushort4 hh, ll;
  split2(nx * inv, hh.x, ll.x);
  split2(ny * inv, hh.y, ll.y);
  split2(nz * inv, hh.z, ll.z);
  split2(nw * inv, hh.w, ll.w);
  *reinterpret_cast<ushort4*>(&yh[off]) = hh;
  *reinterpret_cast<ushort4*>(&yl[off]) = ll;
}

// ---------------------------------------------------------------------------
extern "C" void kernel_launch(void* const* d_in, const int* in_sizes, int n_in,
                              void* d_out, int out_size, void* d_ws, size_t ws_size,
                              hipStream_t stream)
{
  const float* x    = (const float*)d_in[0];
  const float* wqkv = (const float*)d_in[1];
  const float* wout = (const float*)d_in[2];
  const float* bout = (const float*)d_in[3];
  const float* rxth = (const float*)d_in[4];
  const float* ryth = (const float*)d_in[5];
  const float* rang = (const float*)d_in[6];
  float* out = (float*)d_out;

  uint8_t* w8 = (uint8_t*)d_ws;
  float* Tg = (float*)w8;                                  //   4 KB
  float* p0 = (float*)(w8 + 4096);                         //  24 MB (8192x768 f32)
  uint8_t* bb = w8 + 4096 + (size_t)8192 * 768 * 4;
  unsigned short* xh  = (unsigned short*)bb;               // 4 MB
  unsigned short* xl  = xh + (size_t)8192 * 256;           // 4 MB
  unsigned short* wh  = xl + (size_t)8192 * 256;           // 384 KB
  unsigned short* wl  = wh + (size_t)768 * 256;            // 384 KB
  unsigned short* woh = wl + (size_t)768 * 256;            // 128 KB
  unsigned short* wol = woh + (size_t)256 * 256;           // 128 KB
  unsigned short* yh  = wol + (size_t)256 * 256;           // 4 MB
  unsigned short* yl  = yh + (size_t)8192 * 256;           // 4 MB

  int kinds[20], wires[20];
  compute_ops_host(kinds, wires);
  unsigned long long pk = 0, pw = 0;
  for (int i = 0; i < 20; ++i) {
    pk |= (unsigned long long)(kinds[i] & 3) << (2 * i);
    pw |= (unsigned long long)(wires[i] & 3) << (2 * i);
  }

  hipLaunchKernelGGL(build_tables, dim3(1), dim3(256), 0, stream,
                     rang, rxth, ryth, pk, pw, Tg);
  // fp32 -> bf16 hi/lo splits
  hipLaunchKernelGGL(conv_split, dim3(2048), dim3(256), 0, stream, x, xh, xl, 524288);
  hipLaunchKernelGGL(conv_split, dim3(192), dim3(256), 0, stream, wqkv, wh, wl, 49152);
  hipLaunchKernelGGL(conv_split, dim3(64), dim3(256), 0, stream, wout, woh, wol, 16384);
  // gemm1: qkv = x @ w_qkv^T  (8192x768, K=256), grid (768/64, 8192/128)=768
  hipLaunchKernelGGL(gemm_mfma_split, dim3(12, 64), dim3(256), 0, stream,
                     xh, xl, wh, wl, (const float*)nullptr, p0, 8192, 768, 256);
  hipLaunchKernelGGL(quantum_apply4, dim3(1536), dim3(256), 0, stream, p0, Tg);
  hipLaunchKernelGGL(attn64b, dim3(2048), dim3(256), 0, stream, p0, yh, yl);
  // gemm2: out = y @ w_out^T + b  (8192x256, K=256), grid (256/64, 8192/128)=256
  hipLaunchKernelGGL(gemm_mfma_split, dim3(4, 64), dim3(256), 0, stream,
                     yh, yl, woh, wol, bout, out, 8192, 256, 256);
}

// Round 6
// 96.293 us; speedup vs baseline: 1.5739x; 1.2028x over previous
//
#include <hip/hip_runtime.h>
#include <stdint.h>
#include <stddef.h>

// B=4, T=2048, C=256, H=64, D=4 ; rows = 8192 ; qkv row = [q|k|v] 768 f
typedef __attribute__((ext_vector_type(8))) short short8;
typedef __attribute__((ext_vector_type(4))) float floatx4;

// ---------------------------------------------------------------------------
// Host-side np.random.default_rng(1234) op list (verified R2).
// ---------------------------------------------------------------------------
static void compute_ops_host(int* kinds, int* wires) {
  const uint32_t MULT_A = 0x931e8875u;
  const uint32_t INIT_B = 0x8b51f9ddu, MULT_B = 0x58f38dedu;
  const uint32_t MIX_L = 0xca01f9ddu, MIX_R = 0x4973f715u;
  uint32_t hc = 0x43b0d7e5u;
  auto hashmix = [&](uint32_t v) -> uint32_t {
    v ^= hc; hc *= MULT_A; v *= hc; v ^= v >> 16; return v;
  };
  auto mix = [&](uint32_t x, uint32_t y) -> uint32_t {
    uint32_t r = (x * MIX_L) - (y * MIX_R); r ^= r >> 16; return r;
  };
  uint32_t pool[4];
  for (int i = 0; i < 4; ++i) pool[i] = hashmix(i == 0 ? 1234u : 0u);
  for (int s = 0; s < 4; ++s)
    for (int d = 0; d < 4; ++d)
      if (s != d) pool[d] = mix(pool[d], hashmix(pool[s]));
  uint32_t st32[8];
  uint32_t hcb = INIT_B;
  for (int i = 0; i < 8; ++i) {
    uint32_t dv = pool[i & 3];
    dv ^= hcb; hcb *= MULT_B; dv *= hcb; dv ^= dv >> 16;
    st32[i] = dv;
  }
  uint64_t s64[4];
  for (int k = 0; k < 4; ++k) s64[k] = (uint64_t)st32[2 * k] | ((uint64_t)st32[2 * k + 1] << 32);
  const __uint128_t M = ((__uint128_t)0x2360ed051fc65da4ULL << 64) | 0x4385df649fccf645ULL;
  __uint128_t initstate = ((__uint128_t)s64[0] << 64) | s64[1];
  __uint128_t inc = ((((__uint128_t)s64[2] << 64) | s64[3]) << 1) | (__uint128_t)1;
  __uint128_t state = inc;
  state += initstate;
  state = state * M + inc;
  bool has = false; uint32_t hbuf = 0;
  auto next32 = [&]() -> uint32_t {
    if (has) { has = false; return hbuf; }
    state = state * M + inc;
    uint64_t hi = (uint64_t)(state >> 64), lo = (uint64_t)state;
    uint64_t x = hi ^ lo;
    unsigned rot = (unsigned)(state >> 122) & 63u;
    uint64_t o = (x >> rot) | (x << ((64u - rot) & 63u));
    has = true; hbuf = (uint32_t)(o >> 32);
    return (uint32_t)o;
  };
  for (int i = 0; i < 20; ++i) {
    kinds[i] = (int)(((uint64_t)next32() * 4ull) >> 32);
    wires[i] = (int)(((uint64_t)next32() * 4ull) >> 32);
  }
}

// ---------------------------------------------------------------------------
// Build the 3^4 contraction tensors T[w][27][4] from the fixed circuit.
// ---------------------------------------------------------------------------
__global__ __launch_bounds__(256) void build_tables(
    const float* __restrict__ rand_angles, const float* __restrict__ rx_theta,
    const float* __restrict__ ry_theta, unsigned long long kinds,
    unsigned long long wires, float* __restrict__ Tg)
{
  __shared__ float Ur[16][16], Ui[16][16];
  __shared__ float Msh[4][16][16];
  const int tid = threadIdx.x;
  {
    int i = tid >> 4, j = tid & 15;
    Ur[i][j] = (i == j) ? 1.0f : 0.0f;
    Ui[i][j] = 0.0f;
  }
  __syncthreads();
  for (int g = 0; g < 28; ++g) {
    int kind, w; float th;
    if (g < 20) {
      kind = (int)((kinds >> (2 * g)) & 3ull);
      w = (int)((wires >> (2 * g)) & 3ull);
      th = rand_angles[g];
    } else {
      int e = g - 20;
      w = e >> 1;
      kind = (e & 1) ? 1 : 0;
      th = (e & 1) ? ry_theta[0] : rx_theta[0];
    }
    if (kind == 3) {
      int mc = 8 >> w, mt = 8 >> ((w + 1) & 3);
      if (tid < 64) {
        int pi = tid >> 4, j = tid & 15;
        int i = mc, pbit = 0;
        for (int b = 3; b >= 0; --b) {
          int mask = 1 << b;
          if (mask != mc && mask != mt) { i |= ((pi >> pbit) & 1) << b; pbit++; }
        }
        int i2 = i | mt;
        float tr = Ur[i][j], ti = Ui[i][j];
        Ur[i][j] = Ur[i2][j]; Ui[i][j] = Ui[i2][j];
        Ur[i2][j] = tr; Ui[i2][j] = ti;
      }
    } else {
      float s, c;
      sincosf(th * 0.5f, &s, &c);
      float g00r, g00i, g01r, g01i, g10r, g10i, g11r, g11i;
      if (kind == 0) {
        g00r = c; g00i = 0; g01r = 0; g01i = -s; g10r = 0; g10i = -s; g11r = c; g11i = 0;
      } else if (kind == 1) {
        g00r = c; g00i = 0; g01r = -s; g01i = 0; g10r = s; g10i = 0; g11r = c; g11i = 0;
      } else {
        g00r = c; g00i = -s; g01r = 0; g01i = 0; g10r = 0; g10i = 0; g11r = c; g11i = s;
      }
      if (tid < 128) {
        int p = tid >> 4, j = tid & 15;
        int mb = 3 - w;
        int i0 = ((p >> mb) << (mb + 1)) | (p & ((1 << mb) - 1));
        int i1 = i0 | (1 << mb);
        float ar = Ur[i0][j], ai = Ui[i0][j];
        float br = Ur[i1][j], bi = Ui[i1][j];
        Ur[i0][j] = g00r * ar - g00i * ai + g01r * br - g01i * bi;
        Ui[i0][j] = g00r * ai + g00i * ar + g01r * bi + g01i * br;
        Ur[i1][j] = g10r * ar - g10i * ai + g11r * br - g11i * bi;
        Ui[i1][j] = g10r * ai + g10i * ar + g11r * bi + g11i * br;
      }
    }
    __syncthreads();
  }
  {
    int j = tid >> 4, k = tid & 15;
    float m0 = 0, m1 = 0, m2 = 0, m3 = 0;
#pragma unroll
    for (int l = 0; l < 16; ++l) {
      float p = Ur[l][j] * Ur[l][k] + Ui[l][j] * Ui[l][k];
      m0 += (l & 8) ? -p : p;
      m1 += (l & 4) ? -p : p;
      m2 += (l & 2) ? -p : p;
      m3 += (l & 1) ? -p : p;
    }
    Msh[0][j][k] = m0; Msh[1][j][k] = m1; Msh[2][j][k] = m2; Msh[3][j][k] = m3;
  }
  __syncthreads();
  if (tid < 81) {
    int e4 = tid % 3, r = tid / 3;
    int ee0 = r / 9, ee1 = (r / 3) % 3, ee2 = r % 3;
    int ee[4] = { ee0, ee1, ee2, e4 };
    float s0 = 0, s1 = 0, s2 = 0, s3 = 0;
    for (int m = 0; m < 16; ++m) {
      int j = 0, k = 0; float coef = 1.0f;
      for (int i = 0; i < 4; ++i) {
        int o = (m >> i) & 1;
        int e = ee[i];
        int bj, bk; float c;
        if (e == 2)      { bj = o; bk = 1 - o; c = 0.5f; }
        else if (e == 1) { bj = o; bk = o;     c = o ? -0.5f : 0.5f; }
        else             { bj = o; bk = o;     c = 0.5f; }
        j |= bj << (3 - i); k |= bk << (3 - i);
        coef *= c;
      }
      s0 += coef * Msh[0][j][k]; s1 += coef * Msh[1][j][k];
      s2 += coef * Msh[2][j][k]; s3 += coef * Msh[3][j][k];
    }
    Tg[(0 * 27 + r) * 4 + e4] = s0;
    Tg[(1 * 27 + r) * 4 + e4] = s1;
    Tg[(2 * 27 + r) * 4 + e4] = s2;
    Tg[(3 * 27 + r) * 4 + e4] = s3;
  }
  if (tid >= 81 && tid < 108) {
    int r = tid - 81;
    for (int w = 0; w < 4; ++w) Tg[(w * 27 + r) * 4 + 3] = 0.0f;
  }
}

// ---------------------------------------------------------------------------
// bf16 hi/lo split helpers.
// ---------------------------------------------------------------------------
static __device__ __forceinline__ unsigned short bf16_rn(float x) {
  uint32_t u = __float_as_uint(x);
  return (unsigned short)((u + 0x7FFFu + ((u >> 16) & 1u)) >> 16);
}
static __device__ __forceinline__ void split2(float x, unsigned short& h, unsigned short& l) {
  h = bf16_rn(x);
  float hf = __uint_as_float(((uint32_t)h) << 16);
  l = bf16_rn(x - hf);
}

__global__ __launch_bounds__(256) void conv_split(
    const float* __restrict__ in, unsigned short* __restrict__ h,
    unsigned short* __restrict__ l, int n4)
{
  int i = blockIdx.x * 256 + threadIdx.x;
  if (i >= n4) return;
  float4 v = *reinterpret_cast<const float4*>(&in[(size_t)i * 4]);
  ushort4 hh, ll;
  split2(v.x, hh.x, ll.x);
  split2(v.y, hh.y, ll.y);
  split2(v.z, hh.z, ll.z);
  split2(v.w, hh.w, ll.w);
  *reinterpret_cast<ushort4*>(&h[(size_t)i * 4]) = hh;
  *reinterpret_cast<ushort4*>(&l[(size_t)i * 4]) = ll;
}

// ---------------------------------------------------------------------------
// MFMA split-bf16 GEMM (unchanged from R5, verified).
// ---------------------------------------------------------------------------
__global__ __launch_bounds__(256) void gemm_mfma_split(
    const unsigned short* __restrict__ Ah, const unsigned short* __restrict__ Al,
    const unsigned short* __restrict__ Bh, const unsigned short* __restrict__ Bl,
    const float* __restrict__ bias, float* __restrict__ C,
    int M, int N, int K)
{
  __shared__ __align__(16) unsigned short sAh[128 * 32];
  __shared__ __align__(16) unsigned short sAl[128 * 32];
  __shared__ __align__(16) unsigned short sBh[64 * 32];
  __shared__ __align__(16) unsigned short sBl[64 * 32];
  const int tid = threadIdx.x;
  const int bm = blockIdx.y * 128, bn = blockIdx.x * 64;
  const int wave = tid >> 6, lane = tid & 63;
  const int wm = wave >> 1, wn = wave & 1;
  const int fr = lane & 15, fg = lane >> 4;
  floatx4 acc[4][2] = {};
  for (int k0 = 0; k0 < K; k0 += 32) {
    __syncthreads();
#pragma unroll
    for (int rd = 0; rd < 2; ++rd) {
      int q = tid + rd * 256;
      int r = q >> 2, c8 = (q & 3) * 8;
      size_t go = (size_t)(bm + r) * K + (k0 + c8);
      *reinterpret_cast<uint4*>(&sAh[q * 8]) = *reinterpret_cast<const uint4*>(&Ah[go]);
      *reinterpret_cast<uint4*>(&sAl[q * 8]) = *reinterpret_cast<const uint4*>(&Al[go]);
    }
    {
      int r = tid >> 2, c8 = (tid & 3) * 8;
      size_t go = (size_t)(bn + r) * K + (k0 + c8);
      *reinterpret_cast<uint4*>(&sBh[tid * 8]) = *reinterpret_cast<const uint4*>(&Bh[go]);
      *reinterpret_cast<uint4*>(&sBl[tid * 8]) = *reinterpret_cast<const uint4*>(&Bl[go]);
    }
    __syncthreads();
    short8 a_h[4], a_l[4], b_h[2], b_l[2];
#pragma unroll
    for (int fm = 0; fm < 4; ++fm) {
      int row = wm * 64 + fm * 16 + fr;
      a_h[fm] = *reinterpret_cast<const short8*>(&sAh[row * 32 + fg * 8]);
      a_l[fm] = *reinterpret_cast<const short8*>(&sAl[row * 32 + fg * 8]);
    }
#pragma unroll
    for (int fn = 0; fn < 2; ++fn) {
      int row = wn * 32 + fn * 16 + fr;
      b_h[fn] = *reinterpret_cast<const short8*>(&sBh[row * 32 + fg * 8]);
      b_l[fn] = *reinterpret_cast<const short8*>(&sBl[row * 32 + fg * 8]);
    }
#pragma unroll
    for (int fm = 0; fm < 4; ++fm)
#pragma unroll
      for (int fn = 0; fn < 2; ++fn) {
        acc[fm][fn] = __builtin_amdgcn_mfma_f32_16x16x32_bf16(a_h[fm], b_h[fn], acc[fm][fn], 0, 0, 0);
        acc[fm][fn] = __builtin_amdgcn_mfma_f32_16x16x32_bf16(a_h[fm], b_l[fn], acc[fm][fn], 0, 0, 0);
        acc[fm][fn] = __builtin_amdgcn_mfma_f32_16x16x32_bf16(a_l[fm], b_h[fn], acc[fm][fn], 0, 0, 0);
      }
  }
#pragma unroll
  for (int fm = 0; fm < 4; ++fm) {
    int rowb = bm + wm * 64 + fm * 16 + fg * 4;
#pragma unroll
    for (int fn = 0; fn < 2; ++fn) {
      int col = bn + wn * 32 + fn * 16 + fr;
      float bv = (bias != nullptr) ? bias[col] : 0.0f;
#pragma unroll
      for (int r = 0; r < 4; ++r)
        C[(size_t)(rowb + r) * N + col] = acc[fm][fn][r] + bv;
    }
  }
}

// ---------------------------------------------------------------------------
// Quantum transform, 1 vector/thread. T read via wave-uniform global loads
// (compiler scalarizes to s_load; zero LDS, low VGPR -> high occupancy).
// ---------------------------------------------------------------------------
__global__ __launch_bounds__(256) void quantum_apply1(
    float* __restrict__ p0, const float* __restrict__ Tg)
{
  size_t base = ((size_t)blockIdx.x * 256 + threadIdx.x) * 4;
  float4 A = *reinterpret_cast<const float4*>(&p0[base]);
  float cv[4], sv[4];
  __sincosf(A.x, &sv[0], &cv[0]);
  __sincosf(A.y, &sv[1], &cv[1]);
  __sincosf(A.z, &sv[2], &cv[2]);
  __sincosf(A.w, &sv[3], &cv[3]);
  float z[4];
#pragma unroll
  for (int w = 0; w < 4; ++w) {
    float a1_ = 0.f;
#pragma unroll
    for (int e1 = 0; e1 < 3; ++e1) {
      float a2_ = 0.f;
#pragma unroll
      for (int e2 = 0; e2 < 3; ++e2) {
        float a3_ = 0.f;
#pragma unroll
        for (int e3 = 0; e3 < 3; ++e3) {
          const float4 t4 = *reinterpret_cast<const float4*>(
              &Tg[(w * 27 + e1 * 9 + e2 * 3 + e3) * 4]);
          float inner = fmaf(sv[3], t4.z, fmaf(cv[3], t4.y, t4.x));
          if (e3 == 0)      a3_ += inner;
          else if (e3 == 1) a3_ = fmaf(inner, cv[2], a3_);
          else              a3_ = fmaf(inner, sv[2], a3_);
        }
        if (e2 == 0)      a2_ += a3_;
        else if (e2 == 1) a2_ = fmaf(a3_, cv[1], a2_);
        else              a2_ = fmaf(a3_, sv[1], a2_);
      }
      if (e1 == 0)      a1_ += a2_;
      else if (e1 == 1) a1_ = fmaf(a2_, cv[0], a1_);
      else              a1_ = fmaf(a2_, sv[0], a1_);
    }
    z[w] = a1_;
  }
  *reinterpret_cast<float4*>(&p0[base]) = make_float4(z[0], z[1], z[2], z[3]);
}

// ---------------------------------------------------------------------------
// Attention across heads (unchanged from R5, verified).
// ---------------------------------------------------------------------------
__global__ __launch_bounds__(256) void attn64b(
    const float* __restrict__ qkv, unsigned short* __restrict__ yh,
    unsigned short* __restrict__ yl)
{
  __shared__ float Ksh[4][64][4];
  __shared__ float Vsh[4][64][4];
  const int wave = threadIdx.x >> 6, lane = threadIdx.x & 63;
  const int posIdx = blockIdx.x * 4 + wave;   // b*2048 + pos
  const float* row = qkv + (size_t)posIdx * 768;
  float4 q = *reinterpret_cast<const float4*>(&row[lane * 4]);
  *reinterpret_cast<float4*>(&Ksh[wave][lane][0]) =
      *reinterpret_cast<const float4*>(&row[256 + lane * 4]);
  *reinterpret_cast<float4*>(&Vsh[wave][lane][0]) =
      *reinterpret_cast<const float4*>(&row[512 + lane * 4]);
  __syncthreads();
  float nx = 0, ny = 0, nz = 0, nw = 0, den = 0;
#pragma unroll
  for (int ss = 0; ss < 64; ++ss) {
    float d = q.x * Ksh[wave][ss][0] + q.y * Ksh[wave][ss][1] +
              q.z * Ksh[wave][ss][2] + q.w * Ksh[wave][ss][3];
    float e = __expf(d * 0.5f);
    den += e;
    nx = fmaf(e, Vsh[wave][ss][0], nx);
    ny = fmaf(e, Vsh[wave][ss][1], ny);
    nz = fmaf(e, Vsh[wave][ss][2], nz);
    nw = fmaf(e, Vsh[wave][ss][3], nw);
  }
  float inv = 1.0f / den;
  const int b = posIdx >> 11, pos = posIdx & 2047;
  size_t off = (((size_t)(b * 64 + lane)) * 2048 + pos) * 4;
  ushort4 hh, ll;
  split2(nx * inv, hh.x, ll.x);
  split2(ny * inv, hh.y, ll.y);
  split2(nz * inv, hh.z, ll.z);
  split2(nw * inv, hh.w, ll.w);
  *reinterpret_cast<ushort4*>(&yh[off]) = hh;
  *reinterpret_cast<ushort4*>(&yl[off]) = ll;
}

// ---------------------------------------------------------------------------
extern "C" void kernel_launch(void* const* d_in, const int* in_sizes, int n_in,
                              void* d_out, int out_size, void* d_ws, size_t ws_size,
                              hipStream_t stream)
{
  const float* x    = (const float*)d_in[0];
  const float* wqkv = (const float*)d_in[1];
  const float* wout = (const float*)d_in[2];
  const float* bout = (const float*)d_in[3];
  const float* rxth = (const float*)d_in[4];
  const float* ryth = (const float*)d_in[5];
  const float* rang = (const float*)d_in[6];
  float* out = (float*)d_out;

  uint8_t* w8 = (uint8_t*)d_ws;
  float* Tg = (float*)w8;                                  //   4 KB
  float* p0 = (float*)(w8 + 4096);                         //  24 MB (8192x768 f32)
  uint8_t* bb = w8 + 4096 + (size_t)8192 * 768 * 4;
  unsigned short* xh  = (unsigned short*)bb;               // 4 MB
  unsigned short* xl  = xh + (size_t)8192 * 256;           // 4 MB
  unsigned short* wh  = xl + (size_t)8192 * 256;           // 384 KB
  unsigned short* wl  = wh + (size_t)768 * 256;            // 384 KB
  unsigned short* woh = wl + (size_t)768 * 256;            // 128 KB
  unsigned short* wol = woh + (size_t)256 * 256;           // 128 KB
  unsigned short* yh  = wol + (size_t)256 * 256;           // 4 MB
  unsigned short* yl  = yh + (size_t)8192 * 256;           // 4 MB

  int kinds[20], wires[20];
  compute_ops_host(kinds, wires);
  unsigned long long pk = 0, pw = 0;
  for (int i = 0; i < 20; ++i) {
    pk |= (unsigned long long)(kinds[i] & 3) << (2 * i);
    pw |= (unsigned long long)(wires[i] & 3) << (2 * i);
  }

  hipLaunchKernelGGL(build_tables, dim3(1), dim3(256), 0, stream,
                     rang, rxth, ryth, pk, pw, Tg);
  hipLaunchKernelGGL(conv_split, dim3(2048), dim3(256), 0, stream, x, xh, xl, 524288);
  hipLaunchKernelGGL(conv_split, dim3(192), dim3(256), 0, stream, wqkv, wh, wl, 49152);
  hipLaunchKernelGGL(conv_split, dim3(64), dim3(256), 0, stream, wout, woh, wol, 16384);
  hipLaunchKernelGGL(gemm_mfma_split, dim3(12, 64), dim3(256), 0, stream,
                     xh, xl, wh, wl, (const float*)nullptr, p0, 8192, 768, 256);
  hipLaunchKernelGGL(quantum_apply1, dim3(6144), dim3(256), 0, stream, p0, Tg);
  hipLaunchKernelGGL(attn64b, dim3(2048), dim3(256), 0, stream, p0, yh, yl);
  hipLaunchKernelGGL(gemm_mfma_split, dim3(4, 64), dim3(256), 0, stream,
                     yh, yl, woh, wol, bout, out, 8192, 256, 256);
}

// Round 7
// 95.767 us; speedup vs baseline: 1.5826x; 1.0055x over previous
//
#include <hip/hip_runtime.h>
#include <stdint.h>
#include <stddef.h>

// B=4, T=2048, C=256, H=64, D=4 ; rows = 8192 ; qkv row = [q|k|v] 768 f
typedef __attribute__((ext_vector_type(8))) short short8;
typedef __attribute__((ext_vector_type(8))) unsigned short ushort8v;
typedef __attribute__((ext_vector_type(4))) float floatx4;

// ---------------------------------------------------------------------------
// Host-side np.random.default_rng(1234) op list (verified R2).
// ---------------------------------------------------------------------------
static void compute_ops_host(int* kinds, int* wires) {
  const uint32_t MULT_A = 0x931e8875u;
  const uint32_t INIT_B = 0x8b51f9ddu, MULT_B = 0x58f38dedu;
  const uint32_t MIX_L = 0xca01f9ddu, MIX_R = 0x4973f715u;
  uint32_t hc = 0x43b0d7e5u;
  auto hashmix = [&](uint32_t v) -> uint32_t {
    v ^= hc; hc *= MULT_A; v *= hc; v ^= v >> 16; return v;
  };
  auto mix = [&](uint32_t x, uint32_t y) -> uint32_t {
    uint32_t r = (x * MIX_L) - (y * MIX_R); r ^= r >> 16; return r;
  };
  uint32_t pool[4];
  for (int i = 0; i < 4; ++i) pool[i] = hashmix(i == 0 ? 1234u : 0u);
  for (int s = 0; s < 4; ++s)
    for (int d = 0; d < 4; ++d)
      if (s != d) pool[d] = mix(pool[d], hashmix(pool[s]));
  uint32_t st32[8];
  uint32_t hcb = INIT_B;
  for (int i = 0; i < 8; ++i) {
    uint32_t dv = pool[i & 3];
    dv ^= hcb; hcb *= MULT_B; dv *= hcb; dv ^= dv >> 16;
    st32[i] = dv;
  }
  uint64_t s64[4];
  for (int k = 0; k < 4; ++k) s64[k] = (uint64_t)st32[2 * k] | ((uint64_t)st32[2 * k + 1] << 32);
  const __uint128_t M = ((__uint128_t)0x2360ed051fc65da4ULL << 64) | 0x4385df649fccf645ULL;
  __uint128_t initstate = ((__uint128_t)s64[0] << 64) | s64[1];
  __uint128_t inc = ((((__uint128_t)s64[2] << 64) | s64[3]) << 1) | (__uint128_t)1;
  __uint128_t state = inc;
  state += initstate;
  state = state * M + inc;
  bool has = false; uint32_t hbuf = 0;
  auto next32 = [&]() -> uint32_t {
    if (has) { has = false; return hbuf; }
    state = state * M + inc;
    uint64_t hi = (uint64_t)(state >> 64), lo = (uint64_t)state;
    uint64_t x = hi ^ lo;
    unsigned rot = (unsigned)(state >> 122) & 63u;
    uint64_t o = (x >> rot) | (x << ((64u - rot) & 63u));
    has = true; hbuf = (uint32_t)(o >> 32);
    return (uint32_t)o;
  };
  for (int i = 0; i < 20; ++i) {
    kinds[i] = (int)(((uint64_t)next32() * 4ull) >> 32);
    wires[i] = (int)(((uint64_t)next32() * 4ull) >> 32);
  }
}

// ---------------------------------------------------------------------------
// Build the 3^4 contraction tensors T[w][27][4] from the fixed circuit.
// ---------------------------------------------------------------------------
__global__ __launch_bounds__(256) void build_tables(
    const float* __restrict__ rand_angles, const float* __restrict__ rx_theta,
    const float* __restrict__ ry_theta, unsigned long long kinds,
    unsigned long long wires, float* __restrict__ Tg)
{
  __shared__ float Ur[16][16], Ui[16][16];
  __shared__ float Msh[4][16][16];
  const int tid = threadIdx.x;
  {
    int i = tid >> 4, j = tid & 15;
    Ur[i][j] = (i == j) ? 1.0f : 0.0f;
    Ui[i][j] = 0.0f;
  }
  __syncthreads();
  for (int g = 0; g < 28; ++g) {
    int kind, w; float th;
    if (g < 20) {
      kind = (int)((kinds >> (2 * g)) & 3ull);
      w = (int)((wires >> (2 * g)) & 3ull);
      th = rand_angles[g];
    } else {
      int e = g - 20;
      w = e >> 1;
      kind = (e & 1) ? 1 : 0;
      th = (e & 1) ? ry_theta[0] : rx_theta[0];
    }
    if (kind == 3) {
      int mc = 8 >> w, mt = 8 >> ((w + 1) & 3);
      if (tid < 64) {
        int pi = tid >> 4, j = tid & 15;
        int i = mc, pbit = 0;
        for (int b = 3; b >= 0; --b) {
          int mask = 1 << b;
          if (mask != mc && mask != mt) { i |= ((pi >> pbit) & 1) << b; pbit++; }
        }
        int i2 = i | mt;
        float tr = Ur[i][j], ti = Ui[i][j];
        Ur[i][j] = Ur[i2][j]; Ui[i][j] = Ui[i2][j];
        Ur[i2][j] = tr; Ui[i2][j] = ti;
      }
    } else {
      float s, c;
      sincosf(th * 0.5f, &s, &c);
      float g00r, g00i, g01r, g01i, g10r, g10i, g11r, g11i;
      if (kind == 0) {
        g00r = c; g00i = 0; g01r = 0; g01i = -s; g10r = 0; g10i = -s; g11r = c; g11i = 0;
      } else if (kind == 1) {
        g00r = c; g00i = 0; g01r = -s; g01i = 0; g10r = s; g10i = 0; g11r = c; g11i = 0;
      } else {
        g00r = c; g00i = -s; g01r = 0; g01i = 0; g10r = 0; g10i = 0; g11r = c; g11i = s;
      }
      if (tid < 128) {
        int p = tid >> 4, j = tid & 15;
        int mb = 3 - w;
        int i0 = ((p >> mb) << (mb + 1)) | (p & ((1 << mb) - 1));
        int i1 = i0 | (1 << mb);
        float ar = Ur[i0][j], ai = Ui[i0][j];
        float br = Ur[i1][j], bi = Ui[i1][j];
        Ur[i0][j] = g00r * ar - g00i * ai + g01r * br - g01i * bi;
        Ui[i0][j] = g00r * ai + g00i * ar + g01r * bi + g01i * br;
        Ur[i1][j] = g10r * ar - g10i * ai + g11r * br - g11i * bi;
        Ui[i1][j] = g10r * ai + g10i * ar + g11r * bi + g11i * br;
      }
    }
    __syncthreads();
  }
  {
    int j = tid >> 4, k = tid & 15;
    float m0 = 0, m1 = 0, m2 = 0, m3 = 0;
#pragma unroll
    for (int l = 0; l < 16; ++l) {
      float p = Ur[l][j] * Ur[l][k] + Ui[l][j] * Ui[l][k];
      m0 += (l & 8) ? -p : p;
      m1 += (l & 4) ? -p : p;
      m2 += (l & 2) ? -p : p;
      m3 += (l & 1) ? -p : p;
    }
    Msh[0][j][k] = m0; Msh[1][j][k] = m1; Msh[2][j][k] = m2; Msh[3][j][k] = m3;
  }
  __syncthreads();
  if (tid < 81) {
    int e4 = tid % 3, r = tid / 3;
    int ee0 = r / 9, ee1 = (r / 3) % 3, ee2 = r % 3;
    int ee[4] = { ee0, ee1, ee2, e4 };
    float s0 = 0, s1 = 0, s2 = 0, s3 = 0;
    for (int m = 0; m < 16; ++m) {
      int j = 0, k = 0; float coef = 1.0f;
      for (int i = 0; i < 4; ++i) {
        int o = (m >> i) & 1;
        int e = ee[i];
        int bj, bk; float c;
        if (e == 2)      { bj = o; bk = 1 - o; c = 0.5f; }
        else if (e == 1) { bj = o; bk = o;     c = o ? -0.5f : 0.5f; }
        else             { bj = o; bk = o;     c = 0.5f; }
        j |= bj << (3 - i); k |= bk << (3 - i);
        coef *= c;
      }
      s0 += coef * Msh[0][j][k]; s1 += coef * Msh[1][j][k];
      s2 += coef * Msh[2][j][k]; s3 += coef * Msh[3][j][k];
    }
    Tg[(0 * 27 + r) * 4 + e4] = s0;
    Tg[(1 * 27 + r) * 4 + e4] = s1;
    Tg[(2 * 27 + r) * 4 + e4] = s2;
    Tg[(3 * 27 + r) * 4 + e4] = s3;
  }
  if (tid >= 81 && tid < 108) {
    int r = tid - 81;
    for (int w = 0; w < 4; ++w) Tg[(w * 27 + r) * 4 + 3] = 0.0f;
  }
}

// ---------------------------------------------------------------------------
// bf16 hi/lo split helpers (RTNE hi, residual lo).
// ---------------------------------------------------------------------------
static __device__ __forceinline__ unsigned short bf16_rn(float x) {
  uint32_t u = __float_as_uint(x);
  return (unsigned short)((u + 0x7FFFu + ((u >> 16) & 1u)) >> 16);
}
static __device__ __forceinline__ void split2(float x, unsigned short& h, unsigned short& l) {
  h = bf16_rn(x);
  float hf = __uint_as_float(((uint32_t)h) << 16);
  l = bf16_rn(x - hf);
}
static __device__ __forceinline__ void split8_store(
    float4 fa, float4 fb, unsigned short* dsth, unsigned short* dstl) {
  float v[8] = { fa.x, fa.y, fa.z, fa.w, fb.x, fb.y, fb.z, fb.w };
  ushort8v hh, ll;
#pragma unroll
  for (int i = 0; i < 8; ++i) {
    unsigned short h, l;
    split2(v[i], h, l);
    hh[i] = h; ll[i] = l;
  }
  *reinterpret_cast<ushort8v*>(dsth) = hh;
  *reinterpret_cast<ushort8v*>(dstl) = ll;
}

// ---------------------------------------------------------------------------
// MFMA GEMM, fp32 inputs split to bf16 hi/lo in staging registers.
// C[M,N] = A[M,K] @ B[N,K]^T (+bias), fp32-accurate via Ah*Bh+Ah*Bl+Al*Bh.
// BM=128, BN=64, BK=32; 4 waves (2m x 2n), wave-tile 64x32 (4x2 16x16 frags).
// ---------------------------------------------------------------------------
__global__ __launch_bounds__(256) void gemm_a32(
    const float* __restrict__ A, const float* __restrict__ B,
    const float* __restrict__ bias, float* __restrict__ C,
    int M, int N, int K)
{
  __shared__ __align__(16) unsigned short sAh[128 * 32];
  __shared__ __align__(16) unsigned short sAl[128 * 32];
  __shared__ __align__(16) unsigned short sBh[64 * 32];
  __shared__ __align__(16) unsigned short sBl[64 * 32];
  const int tid = threadIdx.x;
  const int bm = blockIdx.y * 128, bn = blockIdx.x * 64;
  const int wave = tid >> 6, lane = tid & 63;
  const int wm = wave >> 1, wn = wave & 1;
  const int fr = lane & 15, fg = lane >> 4;
  floatx4 acc[4][2] = {};
  for (int k0 = 0; k0 < K; k0 += 32) {
    __syncthreads();
    // stage A: 128 rows x 32 cols; each thread: 8 fp32 -> 8 bf16 hi + lo
#pragma unroll
    for (int rd = 0; rd < 2; ++rd) {
      int q = tid + rd * 256;               // 0..511 slots of 8 values
      int r = q >> 2, c8 = (q & 3) * 8;
      const float* src = &A[(size_t)(bm + r) * K + (k0 + c8)];
      float4 fa = *reinterpret_cast<const float4*>(src);
      float4 fb = *reinterpret_cast<const float4*>(src + 4);
      split8_store(fa, fb, &sAh[q * 8], &sAl[q * 8]);
    }
    // stage B: 64 rows x 32 cols
    {
      int r = tid >> 2, c8 = (tid & 3) * 8;
      const float* src = &B[(size_t)(bn + r) * K + (k0 + c8)];
      float4 fa = *reinterpret_cast<const float4*>(src);
      float4 fb = *reinterpret_cast<const float4*>(src + 4);
      split8_store(fa, fb, &sBh[tid * 8], &sBl[tid * 8]);
    }
    __syncthreads();
    short8 a_h[4], a_l[4], b_h[2], b_l[2];
#pragma unroll
    for (int fm = 0; fm < 4; ++fm) {
      int row = wm * 64 + fm * 16 + fr;
      a_h[fm] = *reinterpret_cast<const short8*>(&sAh[row * 32 + fg * 8]);
      a_l[fm] = *reinterpret_cast<const short8*>(&sAl[row * 32 + fg * 8]);
    }
#pragma unroll
    for (int fn = 0; fn < 2; ++fn) {
      int row = wn * 32 + fn * 16 + fr;
      b_h[fn] = *reinterpret_cast<const short8*>(&sBh[row * 32 + fg * 8]);
      b_l[fn] = *reinterpret_cast<const short8*>(&sBl[row * 32 + fg * 8]);
    }
#pragma unroll
    for (int fm = 0; fm < 4; ++fm)
#pragma unroll
      for (int fn = 0; fn < 2; ++fn) {
        acc[fm][fn] = __builtin_amdgcn_mfma_f32_16x16x32_bf16(a_h[fm], b_h[fn], acc[fm][fn], 0, 0, 0);
        acc[fm][fn] = __builtin_amdgcn_mfma_f32_16x16x32_bf16(a_h[fm], b_l[fn], acc[fm][fn], 0, 0, 0);
        acc[fm][fn] = __builtin_amdgcn_mfma_f32_16x16x32_bf16(a_l[fm], b_h[fn], acc[fm][fn], 0, 0, 0);
      }
  }
  // epilogue: C/D map col=lane&15, row=(lane>>4)*4+reg (HW-verified)
#pragma unroll
  for (int fm = 0; fm < 4; ++fm) {
    int rowb = bm + wm * 64 + fm * 16 + fg * 4;
#pragma unroll
    for (int fn = 0; fn < 2; ++fn) {
      int col = bn + wn * 32 + fn * 16 + fr;
      float bv = (bias != nullptr) ? bias[col] : 0.0f;
#pragma unroll
      for (int r = 0; r < 4; ++r)
        C[(size_t)(rowb + r) * N + col] = acc[fm][fn][r] + bv;
    }
  }
}

// ---------------------------------------------------------------------------
// Quantum transform of one 4-angle vector via the 3^4 tensor; T read through
// wave-uniform global loads (scalarized to s_load, K$-cached).
// ---------------------------------------------------------------------------
static __device__ __forceinline__ float4 quantum_vec(
    const float* __restrict__ Tg, float4 A)
{
  float cv[4], sv[4];
  __sincosf(A.x, &sv[0], &cv[0]);
  __sincosf(A.y, &sv[1], &cv[1]);
  __sincosf(A.z, &sv[2], &cv[2]);
  __sincosf(A.w, &sv[3], &cv[3]);
  float z[4];
#pragma unroll
  for (int w = 0; w < 4; ++w) {
    float a1_ = 0.f;
#pragma unroll
    for (int e1 = 0; e1 < 3; ++e1) {
      float a2_ = 0.f;
#pragma unroll
      for (int e2 = 0; e2 < 3; ++e2) {
        float a3_ = 0.f;
#pragma unroll
        for (int e3 = 0; e3 < 3; ++e3) {
          const float4 t4 = *reinterpret_cast<const float4*>(
              &Tg[(w * 27 + e1 * 9 + e2 * 3 + e3) * 4]);
          float inner = fmaf(sv[3], t4.z, fmaf(cv[3], t4.y, t4.x));
          if (e3 == 0)      a3_ += inner;
          else if (e3 == 1) a3_ = fmaf(inner, cv[2], a3_);
          else              a3_ = fmaf(inner, sv[2], a3_);
        }
        if (e2 == 0)      a2_ += a3_;
        else if (e2 == 1) a2_ = fmaf(a3_, cv[1], a2_);
        else              a2_ = fmaf(a3_, sv[1], a2_);
      }
      if (e1 == 0)      a1_ += a2_;
      else if (e1 == 1) a1_ = fmaf(a2_, cv[0], a1_);
      else              a1_ = fmaf(a2_, sv[0], a1_);
    }
    z[w] = a1_;
  }
  return make_float4(z[0], z[1], z[2], z[3]);
}

// ---------------------------------------------------------------------------
// Fused quantum + attention-across-heads. Per (b,pos): each lane owns one
// head's q,k,v vector; applies quantum on load; K/V shared via LDS; softmax
// over 64 heads (|z|<=1 -> |score|<=2, no max-sub). Writes y fp32 in the
// (B,H,T,D)-flat layout (= reference's faithful reshape rows).
// ---------------------------------------------------------------------------
__global__ __launch_bounds__(256) void attn_q(
    const float* __restrict__ qkv, const float* __restrict__ Tg,
    float* __restrict__ y)
{
  __shared__ float Ksh[4][64][4];
  __shared__ float Vsh[4][64][4];
  const int wave = threadIdx.x >> 6, lane = threadIdx.x & 63;
  const int posIdx = blockIdx.x * 4 + wave;   // b*2048 + pos
  const float* row = qkv + (size_t)posIdx * 768;
  float4 qa = *reinterpret_cast<const float4*>(&row[lane * 4]);
  float4 ka = *reinterpret_cast<const float4*>(&row[256 + lane * 4]);
  float4 va = *reinterpret_cast<const float4*>(&row[512 + lane * 4]);
  float4 q = quantum_vec(Tg, qa);
  float4 k = quantum_vec(Tg, ka);
  float4 v = quantum_vec(Tg, va);
  *reinterpret_cast<float4*>(&Ksh[wave][lane][0]) = k;
  *reinterpret_cast<float4*>(&Vsh[wave][lane][0]) = v;
  __syncthreads();
  float nx = 0, ny = 0, nz = 0, nw = 0, den = 0;
#pragma unroll
  for (int ss = 0; ss < 64; ++ss) {
    float d = q.x * Ksh[wave][ss][0] + q.y * Ksh[wave][ss][1] +
              q.z * Ksh[wave][ss][2] + q.w * Ksh[wave][ss][3];
    float e = __expf(d * 0.5f);
    den += e;
    nx = fmaf(e, Vsh[wave][ss][0], nx);
    ny = fmaf(e, Vsh[wave][ss][1], ny);
    nz = fmaf(e, Vsh[wave][ss][2], nz);
    nw = fmaf(e, Vsh[wave][ss][3], nw);
  }
  float inv = 1.0f / den;
  const int b = posIdx >> 11, pos = posIdx & 2047;
  *reinterpret_cast<float4*>(&y[(((size_t)(b * 64 + lane)) * 2048 + pos) * 4]) =
      make_float4(nx * inv, ny * inv, nz * inv, nw * inv);
}

// ---------------------------------------------------------------------------
extern "C" void kernel_launch(void* const* d_in, const int* in_sizes, int n_in,
                              void* d_out, int out_size, void* d_ws, size_t ws_size,
                              hipStream_t stream)
{
  const float* x    = (const float*)d_in[0];
  const float* wqkv = (const float*)d_in[1];
  const float* wout = (const float*)d_in[2];
  const float* bout = (const float*)d_in[3];
  const float* rxth = (const float*)d_in[4];
  const float* ryth = (const float*)d_in[5];
  const float* rang = (const float*)d_in[6];
  float* out = (float*)d_out;

  uint8_t* w8 = (uint8_t*)d_ws;
  float* Tg = (float*)w8;                                  //   4 KB
  float* p0 = (float*)(w8 + 4096);                         //  24 MB (8192x768 f32)
  float* y  = p0 + (size_t)8192 * 768;                     //   8 MB (8192x256 f32)

  int kinds[20], wires[20];
  compute_ops_host(kinds, wires);
  unsigned long long pk = 0, pw = 0;
  for (int i = 0; i < 20; ++i) {
    pk |= (unsigned long long)(kinds[i] & 3) << (2 * i);
    pw |= (unsigned long long)(wires[i] & 3) << (2 * i);
  }

  hipLaunchKernelGGL(build_tables, dim3(1), dim3(256), 0, stream,
                     rang, rxth, ryth, pk, pw, Tg);
  // gemm1: p0 = x @ wqkv^T   (8192x768, K=256)
  hipLaunchKernelGGL(gemm_a32, dim3(12, 64), dim3(256), 0, stream,
                     x, wqkv, (const float*)nullptr, p0, 8192, 768, 256);
  // fused quantum + attention
  hipLaunchKernelGGL(attn_q, dim3(2048), dim3(256), 0, stream, p0, Tg, y);
  // gemm2: out = y @ wout^T + bias   (8192x256, K=256)
  hipLaunchKernelGGL(gemm_a32, dim3(4, 64), dim3(256), 0, stream,
                     y, wout, bout, out, 8192, 256, 256);
}

// Round 8
// 94.171 us; speedup vs baseline: 1.6094x; 1.0169x over previous
//
#include <hip/hip_runtime.h>
#include <stdint.h>
#include <stddef.h>

// B=4, T=2048, C=256, H=64, D=4 ; rows = 8192 ; qkv row = [q|k|v] 768 f
typedef __attribute__((ext_vector_type(8))) short short8;
typedef __attribute__((ext_vector_type(8))) unsigned short ushort8v;
typedef __attribute__((ext_vector_type(4))) float floatx4;

// ---------------------------------------------------------------------------
// Host-side np.random.default_rng(1234) op list (verified R2).
// ---------------------------------------------------------------------------
static void compute_ops_host(int* kinds, int* wires) {
  const uint32_t MULT_A = 0x931e8875u;
  const uint32_t INIT_B = 0x8b51f9ddu, MULT_B = 0x58f38dedu;
  const uint32_t MIX_L = 0xca01f9ddu, MIX_R = 0x4973f715u;
  uint32_t hc = 0x43b0d7e5u;
  auto hashmix = [&](uint32_t v) -> uint32_t {
    v ^= hc; hc *= MULT_A; v *= hc; v ^= v >> 16; return v;
  };
  auto mix = [&](uint32_t x, uint32_t y) -> uint32_t {
    uint32_t r = (x * MIX_L) - (y * MIX_R); r ^= r >> 16; return r;
  };
  uint32_t pool[4];
  for (int i = 0; i < 4; ++i) pool[i] = hashmix(i == 0 ? 1234u : 0u);
  for (int s = 0; s < 4; ++s)
    for (int d = 0; d < 4; ++d)
      if (s != d) pool[d] = mix(pool[d], hashmix(pool[s]));
  uint32_t st32[8];
  uint32_t hcb = INIT_B;
  for (int i = 0; i < 8; ++i) {
    uint32_t dv = pool[i & 3];
    dv ^= hcb; hcb *= MULT_B; dv *= hcb; dv ^= dv >> 16;
    st32[i] = dv;
  }
  uint64_t s64[4];
  for (int k = 0; k < 4; ++k) s64[k] = (uint64_t)st32[2 * k] | ((uint64_t)st32[2 * k + 1] << 32);
  const __uint128_t M = ((__uint128_t)0x2360ed051fc65da4ULL << 64) | 0x4385df649fccf645ULL;
  __uint128_t initstate = ((__uint128_t)s64[0] << 64) | s64[1];
  __uint128_t inc = ((((__uint128_t)s64[2] << 64) | s64[3]) << 1) | (__uint128_t)1;
  __uint128_t state = inc;
  state += initstate;
  state = state * M + inc;
  bool has = false; uint32_t hbuf = 0;
  auto next32 = [&]() -> uint32_t {
    if (has) { has = false; return hbuf; }
    state = state * M + inc;
    uint64_t hi = (uint64_t)(state >> 64), lo = (uint64_t)state;
    uint64_t x = hi ^ lo;
    unsigned rot = (unsigned)(state >> 122) & 63u;
    uint64_t o = (x >> rot) | (x << ((64u - rot) & 63u));
    has = true; hbuf = (uint32_t)(o >> 32);
    return (uint32_t)o;
  };
  for (int i = 0; i < 20; ++i) {
    kinds[i] = (int)(((uint64_t)next32() * 4ull) >> 32);
    wires[i] = (int)(((uint64_t)next32() * 4ull) >> 32);
  }
}

// ---------------------------------------------------------------------------
// Build the 3^4 contraction tensors T[w][27][4] from the fixed circuit.
// ---------------------------------------------------------------------------
__global__ __launch_bounds__(256) void build_tables(
    const float* __restrict__ rand_angles, const float* __restrict__ rx_theta,
    const float* __restrict__ ry_theta, unsigned long long kinds,
    unsigned long long wires, float* __restrict__ Tg)
{
  __shared__ float Ur[16][16], Ui[16][16];
  __shared__ float Msh[4][16][16];
  const int tid = threadIdx.x;
  {
    int i = tid >> 4, j = tid & 15;
    Ur[i][j] = (i == j) ? 1.0f : 0.0f;
    Ui[i][j] = 0.0f;
  }
  __syncthreads();
  for (int g = 0; g < 28; ++g) {
    int kind, w; float th;
    if (g < 20) {
      kind = (int)((kinds >> (2 * g)) & 3ull);
      w = (int)((wires >> (2 * g)) & 3ull);
      th = rand_angles[g];
    } else {
      int e = g - 20;
      w = e >> 1;
      kind = (e & 1) ? 1 : 0;
      th = (e & 1) ? ry_theta[0] : rx_theta[0];
    }
    if (kind == 3) {
      int mc = 8 >> w, mt = 8 >> ((w + 1) & 3);
      if (tid < 64) {
        int pi = tid >> 4, j = tid & 15;
        int i = mc, pbit = 0;
        for (int b = 3; b >= 0; --b) {
          int mask = 1 << b;
          if (mask != mc && mask != mt) { i |= ((pi >> pbit) & 1) << b; pbit++; }
        }
        int i2 = i | mt;
        float tr = Ur[i][j], ti = Ui[i][j];
        Ur[i][j] = Ur[i2][j]; Ui[i][j] = Ui[i2][j];
        Ur[i2][j] = tr; Ui[i2][j] = ti;
      }
    } else {
      float s, c;
      sincosf(th * 0.5f, &s, &c);
      float g00r, g00i, g01r, g01i, g10r, g10i, g11r, g11i;
      if (kind == 0) {
        g00r = c; g00i = 0; g01r = 0; g01i = -s; g10r = 0; g10i = -s; g11r = c; g11i = 0;
      } else if (kind == 1) {
        g00r = c; g00i = 0; g01r = -s; g01i = 0; g10r = s; g10i = 0; g11r = c; g11i = 0;
      } else {
        g00r = c; g00i = -s; g01r = 0; g01i = 0; g10r = 0; g10i = 0; g11r = c; g11i = s;
      }
      if (tid < 128) {
        int p = tid >> 4, j = tid & 15;
        int mb = 3 - w;
        int i0 = ((p >> mb) << (mb + 1)) | (p & ((1 << mb) - 1));
        int i1 = i0 | (1 << mb);
        float ar = Ur[i0][j], ai = Ui[i0][j];
        float br = Ur[i1][j], bi = Ui[i1][j];
        Ur[i0][j] = g00r * ar - g00i * ai + g01r * br - g01i * bi;
        Ui[i0][j] = g00r * ai + g00i * ar + g01r * bi + g01i * br;
        Ur[i1][j] = g10r * ar - g10i * ai + g11r * br - g11i * bi;
        Ui[i1][j] = g10r * ai + g10i * ar + g11r * bi + g11i * br;
      }
    }
    __syncthreads();
  }
  {
    int j = tid >> 4, k = tid & 15;
    float m0 = 0, m1 = 0, m2 = 0, m3 = 0;
#pragma unroll
    for (int l = 0; l < 16; ++l) {
      float p = Ur[l][j] * Ur[l][k] + Ui[l][j] * Ui[l][k];
      m0 += (l & 8) ? -p : p;
      m1 += (l & 4) ? -p : p;
      m2 += (l & 2) ? -p : p;
      m3 += (l & 1) ? -p : p;
    }
    Msh[0][j][k] = m0; Msh[1][j][k] = m1; Msh[2][j][k] = m2; Msh[3][j][k] = m3;
  }
  __syncthreads();
  if (tid < 81) {
    int e4 = tid % 3, r = tid / 3;
    int ee0 = r / 9, ee1 = (r / 3) % 3, ee2 = r % 3;
    int ee[4] = { ee0, ee1, ee2, e4 };
    float s0 = 0, s1 = 0, s2 = 0, s3 = 0;
    for (int m = 0; m < 16; ++m) {
      int j = 0, k = 0; float coef = 1.0f;
      for (int i = 0; i < 4; ++i) {
        int o = (m >> i) & 1;
        int e = ee[i];
        int bj, bk; float c;
        if (e == 2)      { bj = o; bk = 1 - o; c = 0.5f; }
        else if (e == 1) { bj = o; bk = o;     c = o ? -0.5f : 0.5f; }
        else             { bj = o; bk = o;     c = 0.5f; }
        j |= bj << (3 - i); k |= bk << (3 - i);
        coef *= c;
      }
      s0 += coef * Msh[0][j][k]; s1 += coef * Msh[1][j][k];
      s2 += coef * Msh[2][j][k]; s3 += coef * Msh[3][j][k];
    }
    Tg[(0 * 27 + r) * 4 + e4] = s0;
    Tg[(1 * 27 + r) * 4 + e4] = s1;
    Tg[(2 * 27 + r) * 4 + e4] = s2;
    Tg[(3 * 27 + r) * 4 + e4] = s3;
  }
  if (tid >= 81 && tid < 108) {
    int r = tid - 81;
    for (int w = 0; w < 4; ++w) Tg[(w * 27 + r) * 4 + 3] = 0.0f;
  }
}

// ---------------------------------------------------------------------------
// bf16 hi/lo split helpers (RTNE hi, residual lo).
// ---------------------------------------------------------------------------
static __device__ __forceinline__ unsigned short bf16_rn(float x) {
  uint32_t u = __float_as_uint(x);
  return (unsigned short)((u + 0x7FFFu + ((u >> 16) & 1u)) >> 16);
}
static __device__ __forceinline__ void split2(float x, unsigned short& h, unsigned short& l) {
  h = bf16_rn(x);
  float hf = __uint_as_float(((uint32_t)h) << 16);
  l = bf16_rn(x - hf);
}
static __device__ __forceinline__ void split8_store(
    float4 fa, float4 fb, unsigned short* dsth, unsigned short* dstl) {
  float v[8] = { fa.x, fa.y, fa.z, fa.w, fb.x, fb.y, fb.z, fb.w };
  ushort8v hh, ll;
#pragma unroll
  for (int i = 0; i < 8; ++i) {
    unsigned short h, l;
    split2(v[i], h, l);
    hh[i] = h; ll[i] = l;
  }
  *reinterpret_cast<ushort8v*>(dsth) = hh;
  *reinterpret_cast<ushort8v*>(dstl) = ll;
}

// ---------------------------------------------------------------------------
// MFMA GEMM, fp32 inputs split to bf16 hi/lo in staging registers.
// C[M,N] = A[M,K] @ B[N,K]^T (+bias), fp32-accurate via Ah*Bh+Ah*Bl+Al*Bh.
// BM=128, BN=64, BK=32; 4 waves (2m x 2n), wave-tile 64x32 (4x2 16x16 frags).
// ---------------------------------------------------------------------------
__global__ __launch_bounds__(256) void gemm_a32(
    const float* __restrict__ A, const float* __restrict__ B,
    const float* __restrict__ bias, float* __restrict__ C,
    int M, int N, int K)
{
  __shared__ __align__(16) unsigned short sAh[128 * 32];
  __shared__ __align__(16) unsigned short sAl[128 * 32];
  __shared__ __align__(16) unsigned short sBh[64 * 32];
  __shared__ __align__(16) unsigned short sBl[64 * 32];
  const int tid = threadIdx.x;
  const int bm = blockIdx.y * 128, bn = blockIdx.x * 64;
  const int wave = tid >> 6, lane = tid & 63;
  const int wm = wave >> 1, wn = wave & 1;
  const int fr = lane & 15, fg = lane >> 4;
  floatx4 acc[4][2] = {};
  for (int k0 = 0; k0 < K; k0 += 32) {
    __syncthreads();
#pragma unroll
    for (int rd = 0; rd < 2; ++rd) {
      int q = tid + rd * 256;
      int r = q >> 2, c8 = (q & 3) * 8;
      const float* src = &A[(size_t)(bm + r) * K + (k0 + c8)];
      float4 fa = *reinterpret_cast<const float4*>(src);
      float4 fb = *reinterpret_cast<const float4*>(src + 4);
      split8_store(fa, fb, &sAh[q * 8], &sAl[q * 8]);
    }
    {
      int r = tid >> 2, c8 = (tid & 3) * 8;
      const float* src = &B[(size_t)(bn + r) * K + (k0 + c8)];
      float4 fa = *reinterpret_cast<const float4*>(src);
      float4 fb = *reinterpret_cast<const float4*>(src + 4);
      split8_store(fa, fb, &sBh[tid * 8], &sBl[tid * 8]);
    }
    __syncthreads();
    short8 a_h[4], a_l[4], b_h[2], b_l[2];
#pragma unroll
    for (int fm = 0; fm < 4; ++fm) {
      int row = wm * 64 + fm * 16 + fr;
      a_h[fm] = *reinterpret_cast<const short8*>(&sAh[row * 32 + fg * 8]);
      a_l[fm] = *reinterpret_cast<const short8*>(&sAl[row * 32 + fg * 8]);
    }
#pragma unroll
    for (int fn = 0; fn < 2; ++fn) {
      int row = wn * 32 + fn * 16 + fr;
      b_h[fn] = *reinterpret_cast<const short8*>(&sBh[row * 32 + fg * 8]);
      b_l[fn] = *reinterpret_cast<const short8*>(&sBl[row * 32 + fg * 8]);
    }
#pragma unroll
    for (int fm = 0; fm < 4; ++fm)
#pragma unroll
      for (int fn = 0; fn < 2; ++fn) {
        acc[fm][fn] = __builtin_amdgcn_mfma_f32_16x16x32_bf16(a_h[fm], b_h[fn], acc[fm][fn], 0, 0, 0);
        acc[fm][fn] = __builtin_amdgcn_mfma_f32_16x16x32_bf16(a_h[fm], b_l[fn], acc[fm][fn], 0, 0, 0);
        acc[fm][fn] = __builtin_amdgcn_mfma_f32_16x16x32_bf16(a_l[fm], b_h[fn], acc[fm][fn], 0, 0, 0);
      }
  }
#pragma unroll
  for (int fm = 0; fm < 4; ++fm) {
    int rowb = bm + wm * 64 + fm * 16 + fg * 4;
#pragma unroll
    for (int fn = 0; fn < 2; ++fn) {
      int col = bn + wn * 32 + fn * 16 + fr;
      float bv = (bias != nullptr) ? bias[col] : 0.0f;
#pragma unroll
      for (int r = 0; r < 4; ++r)
        C[(size_t)(rowb + r) * N + col] = acc[fm][fn][r] + bv;
    }
  }
}

// ---------------------------------------------------------------------------
// Quantum transform, 1 vector/thread, streaming (low VGPR, high occupancy).
// T read via wave-uniform global loads (scalarized to s_load, K$-cached).
// ---------------------------------------------------------------------------
__global__ __launch_bounds__(256) void quantum_apply1(
    float* __restrict__ p0, const float* __restrict__ Tg)
{
  size_t base = ((size_t)blockIdx.x * 256 + threadIdx.x) * 4;
  float4 A = *reinterpret_cast<const float4*>(&p0[base]);
  float cv[4], sv[4];
  __sincosf(A.x, &sv[0], &cv[0]);
  __sincosf(A.y, &sv[1], &cv[1]);
  __sincosf(A.z, &sv[2], &cv[2]);
  __sincosf(A.w, &sv[3], &cv[3]);
  float z[4];
#pragma unroll
  for (int w = 0; w < 4; ++w) {
    float a1_ = 0.f;
#pragma unroll
    for (int e1 = 0; e1 < 3; ++e1) {
      float a2_ = 0.f;
#pragma unroll
      for (int e2 = 0; e2 < 3; ++e2) {
        float a3_ = 0.f;
#pragma unroll
        for (int e3 = 0; e3 < 3; ++e3) {
          const float4 t4 = *reinterpret_cast<const float4*>(
              &Tg[(w * 27 + e1 * 9 + e2 * 3 + e3) * 4]);
          float inner = fmaf(sv[3], t4.z, fmaf(cv[3], t4.y, t4.x));
          if (e3 == 0)      a3_ += inner;
          else if (e3 == 1) a3_ = fmaf(inner, cv[2], a3_);
          else              a3_ = fmaf(inner, sv[2], a3_);
        }
        if (e2 == 0)      a2_ += a3_;
        else if (e2 == 1) a2_ = fmaf(a3_, cv[1], a2_);
        else              a2_ = fmaf(a3_, sv[1], a2_);
      }
      if (e1 == 0)      a1_ += a2_;
      else if (e1 == 1) a1_ = fmaf(a2_, cv[0], a1_);
      else              a1_ = fmaf(a2_, sv[0], a1_);
    }
    z[w] = a1_;
  }
  *reinterpret_cast<float4*>(&p0[base]) = make_float4(z[0], z[1], z[2], z[3]);
}

// ---------------------------------------------------------------------------
// Lean attention-across-heads: reads quantum'd p0. Per (b,pos): softmax over
// S=QK^T/2 (64x64), Y = A V. |z|<=1 -> |score|<=2 -> no max-sub.
// Writes y fp32 in (B,H,T,D)-flat layout (= reference reshape rows).
// ---------------------------------------------------------------------------
__global__ __launch_bounds__(256) void attn32(
    const float* __restrict__ qkv, float* __restrict__ y)
{
  __shared__ float Ksh[4][64][4];
  __shared__ float Vsh[4][64][4];
  const int wave = threadIdx.x >> 6, lane = threadIdx.x & 63;
  const int posIdx = blockIdx.x * 4 + wave;   // b*2048 + pos
  const float* row = qkv + (size_t)posIdx * 768;
  float4 q = *reinterpret_cast<const float4*>(&row[lane * 4]);
  *reinterpret_cast<float4*>(&Ksh[wave][lane][0]) =
      *reinterpret_cast<const float4*>(&row[256 + lane * 4]);
  *reinterpret_cast<float4*>(&Vsh[wave][lane][0]) =
      *reinterpret_cast<const float4*>(&row[512 + lane * 4]);
  __syncthreads();
  float nx = 0, ny = 0, nz = 0, nw = 0, den = 0;
#pragma unroll
  for (int ss = 0; ss < 64; ++ss) {
    float d = q.x * Ksh[wave][ss][0] + q.y * Ksh[wave][ss][1] +
              q.z * Ksh[wave][ss][2] + q.w * Ksh[wave][ss][3];
    float e = __expf(d * 0.5f);
    den += e;
    nx = fmaf(e, Vsh[wave][ss][0], nx);
    ny = fmaf(e, Vsh[wave][ss][1], ny);
    nz = fmaf(e, Vsh[wave][ss][2], nz);
    nw = fmaf(e, Vsh[wave][ss][3], nw);
  }
  float inv = 1.0f / den;
  const int b = posIdx >> 11, pos = posIdx & 2047;
  *reinterpret_cast<float4*>(&y[(((size_t)(b * 64 + lane)) * 2048 + pos) * 4]) =
      make_float4(nx * inv, ny * inv, nz * inv, nw * inv);
}

// ---------------------------------------------------------------------------
extern "C" void kernel_launch(void* const* d_in, const int* in_sizes, int n_in,
                              void* d_out, int out_size, void* d_ws, size_t ws_size,
                              hipStream_t stream)
{
  const float* x    = (const float*)d_in[0];
  const float* wqkv = (const float*)d_in[1];
  const float* wout = (const float*)d_in[2];
  const float* bout = (const float*)d_in[3];
  const float* rxth = (const float*)d_in[4];
  const float* ryth = (const float*)d_in[5];
  const float* rang = (const float*)d_in[6];
  float* out = (float*)d_out;

  uint8_t* w8 = (uint8_t*)d_ws;
  float* Tg = (float*)w8;                                  //   4 KB
  float* p0 = (float*)(w8 + 4096);                         //  24 MB (8192x768 f32)
  float* y  = p0 + (size_t)8192 * 768;                     //   8 MB (8192x256 f32)

  int kinds[20], wires[20];
  compute_ops_host(kinds, wires);
  unsigned long long pk = 0, pw = 0;
  for (int i = 0; i < 20; ++i) {
    pk |= (unsigned long long)(kinds[i] & 3) << (2 * i);
    pw |= (unsigned long long)(wires[i] & 3) << (2 * i);
  }

  hipLaunchKernelGGL(build_tables, dim3(1), dim3(256), 0, stream,
                     rang, rxth, ryth, pk, pw, Tg);
  // gemm1: p0 = x @ wqkv^T   (8192x768, K=256)
  hipLaunchKernelGGL(gemm_a32, dim3(12, 64), dim3(256), 0, stream,
                     x, wqkv, (const float*)nullptr, p0, 8192, 768, 256);
  // quantum transform in-place on p0 (1.57M vectors)
  hipLaunchKernelGGL(quantum_apply1, dim3(6144), dim3(256), 0, stream, p0, Tg);
  // attention across heads
  hipLaunchKernelGGL(attn32, dim3(2048), dim3(256), 0, stream, p0, y);
  // gemm2: out = y @ wout^T + bias   (8192x256, K=256)
  hipLaunchKernelGGL(gemm_a32, dim3(4, 64), dim3(256), 0, stream,
                     y, wout, bout, out, 8192, 256, 256);
}